// Round 1
// baseline (636.866 us; speedup 1.0000x reference)
//
#include <hip/hip_runtime.h>

#define NN 50000
#define NE 800000

typedef __attribute__((ext_vector_type(8))) short bf16x8;
typedef __attribute__((ext_vector_type(4))) float f32x4;

__device__ __forceinline__ short f2bf(float f) {
    union { float f; unsigned u; } v; v.f = f;
    return (short)((v.u + 0x7fffu + ((v.u >> 16) & 1u)) >> 16);
}

__device__ __forceinline__ float bf2f(short s) {
    union { unsigned u; float f; } v;
    v.u = ((unsigned)(unsigned short)s) << 16;
    return v.f;
}

__device__ __forceinline__ bf16x8 cvt8(const float* __restrict__ p) {
    const f32x4 a = *(const f32x4*)p;
    const f32x4 b = *(const f32x4*)(p + 4);
    bf16x8 r;
#pragma unroll
    for (int j = 0; j < 4; ++j) { r[j] = f2bf(a[j]); r[j + 4] = f2bf(b[j]); }
    return r;
}

// gW slot map (slot = 8 shorts at gW + slot*8):
// [0,2048) Wm1a | [2048,4096) Wm1b | [4096,4608) W1c | [4608,6656) Wm2 sigma
// [6656,8704) Wu1a | [8704,10752) Wu1b | [10752,12800) Wu2 sigma
#define GW_M1A 0
#define GW_M1B 16384
#define GW_1C  32768
#define GW_M2S 36864
#define GW_U1A 53248
#define GW_U1B 69632
#define GW_U2S 86016
#define GW_TOT 102400

// Stage W (KROWS x 128 row-major fp32) -> LDS bf16 MFMA B-fragments (node_pq path).
template<int KROWS, int NTHREADS>
__device__ __forceinline__ void stage_w(const float* __restrict__ W, short* lds, int tid) {
    constexpr int NSLOT = (KROWS / 32) * 8 * 64;
#pragma unroll 1
    for (int slot = tid; slot < NSLOT; slot += NTHREADS) {
        const int f = slot >> 6, l = slot & 63;
        const int s = f >> 3, t = f & 7;
        const int k0 = 32 * s + ((l >> 4) << 3);
        const int n = 16 * t + (l & 15);
        bf16x8 v;
#pragma unroll
        for (int j = 0; j < 8; ++j) v[j] = f2bf(W[(k0 + j) * 128 + n]);
        *(bf16x8*)(lds + slot * 8) = v;
    }
}

template<int NSLOT, int NTHREADS>
__device__ __forceinline__ void stage_copy(const short* __restrict__ g, short* lds, int tid) {
#pragma unroll
    for (int i = 0; i < NSLOT / NTHREADS; ++i) {
        const int s = tid + i * NTHREADS;
        *(bf16x8*)(lds + (size_t)s * 8) = *(const bf16x8*)(g + (size_t)s * 8);
    }
}

// ---------------- mega kernel: node_pq (blocks 0..511) | preswz (512..561) | hist (562..) ----------------

__global__ __launch_bounds__(256) void mega_kernel(
    const float* __restrict__ h, const float* __restrict__ Wm1,
    const float* __restrict__ bm1, const float* __restrict__ Wm2,
    const float* __restrict__ Wu1, const float* __restrict__ Wu2,
    const int* __restrict__ eidx, short* __restrict__ gW,
    short* __restrict__ Pb, short* __restrict__ Qb, int* __restrict__ cnt)
{
    const int b = blockIdx.x;
    const int tid = threadIdx.x;
    if (b < 512) {
        // ---- node_pq: P~ = h@Wm1a (sigma bf16), Q~ = h@Wm1b + bm1 ----
        __shared__ short sWa[16384];
        __shared__ short sWb[16384];
        stage_w<128, 256>(Wm1, sWa, tid);
        stage_w<128, 256>(Wm1 + 128 * 128, sWb, tid);
        __syncthreads();
        const int wave = tid >> 6, lane = tid & 63;
        const int q = lane >> 4, col = lane & 15;
        float b1v[8];
#pragma unroll
        for (int t = 0; t < 8; ++t) b1v[t] = bm1[t * 16 + col];
        for (int tile = b * 4 + wave; tile < NN / 16; tile += 2048) {
            const int r0 = tile * 16;
            f32x4 aP[8], aQ[8];
#pragma unroll
            for (int t = 0; t < 8; ++t) {
                aP[t] = {0.f, 0.f, 0.f, 0.f};
                const float bb = b1v[t];
                aQ[t] = {bb, bb, bb, bb};
            }
#pragma unroll
            for (int s = 0; s < 4; ++s) {
                const bf16x8 ah = cvt8(&h[(r0 + col) * 128 + s * 32 + q * 8]);
#pragma unroll
                for (int t = 0; t < 8; ++t) {
                    const bf16x8 ba = *(const bf16x8*)(sWa + ((s * 8 + t) * 64 + lane) * 8);
                    const bf16x8 bb = *(const bf16x8*)(sWb + ((s * 8 + t) * 64 + lane) * 8);
                    aP[t] = __builtin_amdgcn_mfma_f32_16x16x32_bf16(ah, ba, aP[t], 0, 0, 0);
                    aQ[t] = __builtin_amdgcn_mfma_f32_16x16x32_bf16(ah, bb, aQ[t], 0, 0, 0);
                }
            }
#pragma unroll
            for (int r = 0; r < 4; ++r) {
                const size_t row = (size_t)(r0 + q * 4 + r) * 128;
                bf16x8 vp, vq;
#pragma unroll
                for (int t = 0; t < 8; ++t) { vp[t] = f2bf(aP[t][r]); vq[t] = f2bf(aQ[t][r]); }
                *(bf16x8*)(Pb + row + col * 8) = vp;
                *(bf16x8*)(Qb + row + col * 8) = vq;
            }
        }
    } else if (b < 562) {
        // ---- preswz: weights -> global bf16 fragments ----
        const int slot = (b - 512) * 256 + tid;
        if (slot < 12800) {
            const float* W; int local; bool sigma = false;
            if (slot < 2048)       { W = Wm1;             local = slot; }
            else if (slot < 4096)  { W = Wm1 + 128 * 128; local = slot - 2048; }
            else if (slot < 4608)  { W = Wm1 + 256 * 128; local = slot - 4096; }
            else if (slot < 6656)  { W = Wm2;             local = slot - 4608; sigma = true; }
            else if (slot < 8704)  { W = Wu1;             local = slot - 6656; }
            else if (slot < 10752) { W = Wu1 + 128 * 128; local = slot - 8704; }
            else                   { W = Wu2;             local = slot - 10752; sigma = true; }
            const int f = local >> 6, l = local & 63;
            const int s = f >> 3, t = f & 7;
            const int k0 = 32 * s + ((l >> 4) << 3);
            const int n = 16 * t + (l & 15);
            bf16x8 v;
#pragma unroll
            for (int j = 0; j < 8; ++j) {
                int k = k0 + j;
                if (sigma) k = (k & 7) * 16 + (k >> 3);
                v[j] = f2bf(W[k * 128 + n]);
            }
            *(bf16x8*)(gW + (size_t)slot * 8) = v;
        }
    } else {
        // ---- hist ----
        const int e = (b - 562) * 256 + tid;
        if (e < NE) atomicAdd(&cnt[eidx[NE + e]], 1);
    }
}

// ---------------- scan ----------------

__global__ __launch_bounds__(1024) void scan1_kernel(const int* __restrict__ cnt,
                                                     int* __restrict__ part,
                                                     int* __restrict__ bsum) {
    __shared__ int s[1024];
    const int t = threadIdx.x;
    const int i = blockIdx.x * 1024 + t;
    const int v = (i < NN) ? cnt[i] : 0;
    int x = v;
    s[t] = x;
    __syncthreads();
    for (int off = 1; off < 1024; off <<= 1) {
        const int y = (t >= off) ? s[t - off] : 0;
        __syncthreads();
        x += y;
        s[t] = x;
        __syncthreads();
    }
    if (i < NN) part[i] = x - v;
    if (t == 1023) bsum[blockIdx.x] = x;
}

__global__ __launch_bounds__(1024) void scan23_kernel(const int* __restrict__ part,
                                                      const int* __restrict__ bsum,
                                                      int* __restrict__ cursor) {
    __shared__ int off;
    if (threadIdx.x == 0) {
        int a = 0;
        for (int bb = 0; bb < (int)blockIdx.x; ++bb) a += bsum[bb];
        off = a;
    }
    __syncthreads();
    const int i = blockIdx.x * 1024 + threadIdx.x;
    if (i < NN) cursor[i] = part[i] + off;
}

// ---------------- scatter: perm edges to sorted order; also permute+cvt ea -> eb (bf16) ----------------

__global__ void scatter_kernel(const int* __restrict__ eidx, int* __restrict__ cursor,
                               const float* __restrict__ ea,
                               int2* __restrict__ sd2, short* __restrict__ eb) {
    const int e = blockIdx.x * blockDim.x + threadIdx.x;
    if (e < NE) {
        const int d = eidx[NE + e];
        const int pos = atomicAdd(&cursor[d], 1);
        sd2[pos] = make_int2(eidx[e], d);
        const float* src = ea + (size_t)e * 32;
        short* dst = eb + (size_t)pos * 32;
#pragma unroll
        for (int j = 0; j < 4; ++j) {
            const f32x4 a = *(const f32x4*)(src + j * 8);
            const f32x4 bq = *(const f32x4*)(src + j * 8 + 4);
            bf16x8 v;
#pragma unroll
            for (int k = 0; k < 4; ++k) { v[k] = f2bf(a[k]); v[4 + k] = f2bf(bq[k]); }
            *(bf16x8*)(dst + j * 8) = v;
        }
    }
}

// ---------------- edge kernel: dst-sorted tiles, segmented reduce, cross-tile pipelined ----------------
// Pipeline: per iteration, the P~/Q~/ea gathers and sd2 load for tile t were issued during
// tile t-1 (sd2 early, gathers mid-layer2), so the ~600-900cy random-gather latency hides
// under layer2 MFMA + segmented reduce. Single register generation for vp/vq/aea (their
// old values die at layer1 before the refill issues). Costs ~+30 VGPR -> 1 block/CU
// (__launch_bounds__(512,2)); traded 16->8 waves/CU for ~2x shorter per-tile span.

__global__ __launch_bounds__(512, 2) void edge_kernel(
    const short* __restrict__ Pb, const short* __restrict__ Qb,
    const short* __restrict__ eb, const short* __restrict__ gW,
    const float* __restrict__ bm2,
    const int2* __restrict__ sd2, float* __restrict__ agg)
{
    __shared__ short sW2[16384];
    __shared__ short sW1c[4096];
    __shared__ short sX[8][16 * 136];
    const int tid = threadIdx.x;
    const int wave = tid >> 6, lane = tid & 63;
    const int q = lane >> 4, col = lane & 15;
    const int NT = NE / 16;
    const int STR = gridDim.x * 8;
    const int tile0 = blockIdx.x * 8 + wave;
    float b2v[8];
#pragma unroll
    for (int t = 0; t < 8; ++t) b2v[t] = bm2[t * 16 + col];

    // prologue: issue first sd2 load, stage weights (hides sd latency), then first gathers
    int2 sd_c[4];
    {
        const int e0 = tile0 * 16;
        const int4 a0 = *(const int4*)(sd2 + e0 + q * 4);
        const int4 a1 = *(const int4*)(sd2 + e0 + q * 4 + 2);
        sd_c[0] = make_int2(a0.x, a0.y); sd_c[1] = make_int2(a0.z, a0.w);
        sd_c[2] = make_int2(a1.x, a1.y); sd_c[3] = make_int2(a1.z, a1.w);
    }
    stage_copy<2048, 512>(gW + GW_M2S, sW2, tid);
    stage_copy<512, 512>(gW + GW_1C, sW1c, tid);
    bf16x8 vp[4], vq[4], aea;
#pragma unroll
    for (int r = 0; r < 4; ++r) {
        vp[r] = *(const bf16x8*)(Pb + (size_t)sd_c[r].x * 128 + col * 8);
        vq[r] = *(const bf16x8*)(Qb + (size_t)sd_c[r].y * 128 + col * 8);
    }
    aea = *(const bf16x8*)(eb + (size_t)(tile0 * 16 + col) * 32 + q * 8);
    __syncthreads();
    short* myX = &sX[wave][0];

    for (int tile = tile0; tile < NT; tile += STR) {
        // next tile index (clamped: last iteration harmlessly re-reads current tile)
        const int tn = (tile + STR < NT) ? (tile + STR) : tile;
        // run-structure mask for current tile
        const int prev3 = __shfl_up(sd_c[3].y, 16);
        unsigned qm = 0;
        if (q > 0 && sd_c[0].y == prev3) qm |= 1u;
        if (sd_c[1].y == sd_c[0].y) qm |= 2u;
        if (sd_c[2].y == sd_c[1].y) qm |= 4u;
        if (sd_c[3].y == sd_c[2].y) qm |= 8u;
        const unsigned o1 = (unsigned)__shfl_xor((int)qm, 16);
        const unsigned o2 = (unsigned)__shfl_xor((int)qm, 32);
        const unsigned o3 = (unsigned)__shfl_xor((int)o1, 32);
        const unsigned eqmask = (qm << (q * 4)) | (o1 << ((q ^ 1) * 4)) |
                                (o2 << ((q ^ 2) * 4)) | (o3 << ((q ^ 3) * 4));
        // issue next-tile sd2 load (latency hidden under layer1 + X)
        int2 sd_n[4];
        {
            const int en = tn * 16;
            const int4 a0 = *(const int4*)(sd2 + en + q * 4);
            const int4 a1 = *(const int4*)(sd2 + en + q * 4 + 2);
            sd_n[0] = make_int2(a0.x, a0.y); sd_n[1] = make_int2(a0.z, a0.w);
            sd_n[2] = make_int2(a1.x, a1.y); sd_n[3] = make_int2(a1.z, a1.w);
        }
        // layer 1: gathered P~[src] + Q~[dst](+b1)  (vp/vq prefetched last iteration)
        f32x4 acc1[8];
#pragma unroll
        for (int r = 0; r < 4; ++r) {
            const bf16x8 vpr = vp[r], vqr = vq[r];
#pragma unroll
            for (int t = 0; t < 8; ++t)
                acc1[t][r] = bf2f(vpr[t]) + bf2f(vqr[t]);
        }
        // + ea @ W1c
#pragma unroll
        for (int t = 0; t < 8; ++t) {
            const bf16x8 bw = *(const bf16x8*)(sW1c + (t * 64 + lane) * 8);
            acc1[t] = __builtin_amdgcn_mfma_f32_16x16x32_bf16(aea, bw, acc1[t], 0, 0, 0);
        }
        // relu -> bf16 -> X~ LDS
#pragma unroll
        for (int r = 0; r < 4; ++r) {
            bf16x8 vx;
#pragma unroll
            for (int t = 0; t < 8; ++t) {
                const float x = acc1[t][r];
                vx[t] = f2bf(x > 0.f ? x : 0.f);
            }
            *(bf16x8*)(myX + (q * 4 + r) * 136 + col * 8) = vx;
        }
        // layer 2, first half (s=0,1)
        f32x4 acc2[8];
#pragma unroll
        for (int t = 0; t < 8; ++t) {
            const float b = b2v[t];
            acc2[t] = {b, b, b, b};
        }
#pragma unroll
        for (int s = 0; s < 2; ++s) {
            const bf16x8 ax = *(const bf16x8*)(myX + col * 136 + s * 32 + q * 8);
#pragma unroll
            for (int t = 0; t < 8; ++t) {
                const bf16x8 bw = *(const bf16x8*)(sW2 + ((s * 8 + t) * 64 + lane) * 8);
                acc2[t] = __builtin_amdgcn_mfma_f32_16x16x32_bf16(ax, bw, acc2[t], 0, 0, 0);
            }
        }
        // prefetch next-tile gathers (old vp/vq/aea dead since layer1; consumed next iter —
        // latency hidden under layer2 second half + reduce + next masks)
#pragma unroll
        for (int r = 0; r < 4; ++r) {
            vp[r] = *(const bf16x8*)(Pb + (size_t)sd_n[r].x * 128 + col * 8);
            vq[r] = *(const bf16x8*)(Qb + (size_t)sd_n[r].y * 128 + col * 8);
        }
        aea = *(const bf16x8*)(eb + (size_t)(tn * 16 + col) * 32 + q * 8);
        // layer 2, second half (s=2,3)
#pragma unroll
        for (int s = 2; s < 4; ++s) {
            const bf16x8 ax = *(const bf16x8*)(myX + col * 136 + s * 32 + q * 8);
#pragma unroll
            for (int t = 0; t < 8; ++t) {
                const bf16x8 bw = *(const bf16x8*)(sW2 + ((s * 8 + t) * 64 + lane) * 8);
                acc2[t] = __builtin_amdgcn_mfma_f32_16x16x32_bf16(ax, bw, acc2[t], 0, 0, 0);
            }
        }
        // segmented reduce + atomics
        if (eqmask == 0xFFFEu) {
#pragma unroll
            for (int t = 0; t < 8; ++t) {
                float m0 = acc2[t][0]; m0 = m0 > 0.f ? m0 : 0.f;
                float m1 = acc2[t][1]; m1 = m1 > 0.f ? m1 : 0.f;
                float m2 = acc2[t][2]; m2 = m2 > 0.f ? m2 : 0.f;
                float m3 = acc2[t][3]; m3 = m3 > 0.f ? m3 : 0.f;
                float s = (m0 + m1) + (m2 + m3);
                s += __shfl_xor(s, 16);
                s += __shfl_xor(s, 32);
                if (q == 0 && s != 0.f)
                    unsafeAtomicAdd(&agg[(size_t)sd_c[0].y * 128 + t * 16 + col], s);
            }
        } else {
            int head[4], qe[4];
#pragma unroll
            for (int r = 0; r < 4; ++r) {
                const int e = q * 4 + r;
                head[r] = !((eqmask >> e) & 1u);
                const unsigned after = ~(eqmask >> (e + 1));
                const int run = __builtin_ctz(after);
                qe[r] = (e + run) >> 2;
            }
#pragma unroll
            for (int t = 0; t < 8; ++t) {
                float m0 = acc2[t][0]; m0 = m0 > 0.f ? m0 : 0.f;
                float m1 = acc2[t][1]; m1 = m1 > 0.f ? m1 : 0.f;
                float m2 = acc2[t][2]; m2 = m2 > 0.f ? m2 : 0.f;
                float m3 = acc2[t][3]; m3 = m3 > 0.f ? m3 : 0.f;
                const float s3 = m3;
                const float s2 = m2 + ((qm & 8u) ? s3 : 0.f);
                const float s1 = m1 + ((qm & 4u) ? s2 : 0.f);
                const float s0 = m0 + ((qm & 2u) ? s1 : 0.f);
                const float p1 = __shfl_xor(s0, 16);
                const float p2 = __shfl_xor(s0, 32);
                const float p3 = __shfl_xor(p1, 32);
                const float seg[4] = {s0, s1, s2, s3};
#pragma unroll
                for (int r = 0; r < 4; ++r) {
                    if (head[r]) {
                        float tot = seg[r];
#pragma unroll
                        for (int j = 1; j < 4; ++j) {
                            if (j > q && j <= qe[r]) {
                                const int jx = j ^ q;
                                tot += (jx == 1) ? p1 : (jx == 2) ? p2 : p3;
                            }
                        }
                        if (tot != 0.f)
                            unsafeAtomicAdd(&agg[(size_t)sd_c[r].y * 128 + t * 16 + col], tot);
                    }
                }
            }
        }
        // rotate pipeline state
#pragma unroll
        for (int r = 0; r < 4; ++r) sd_c[r] = sd_n[r];
    }
}

// ---------------- update MLP + residual ----------------

__global__ __launch_bounds__(512) void update_kernel(
    const float* __restrict__ h, const float* __restrict__ agg,
    const short* __restrict__ gW, const float* __restrict__ bu1,
    const float* __restrict__ bu2, float* __restrict__ out)
{
    __shared__ short sWa[16384];
    __shared__ short sWb[16384];
    __shared__ short sW2[16384];
    __shared__ short sX[8][16 * 136];
    const int tid = threadIdx.x;
    const int wave = tid >> 6, lane = tid & 63;
    const int q = lane >> 4, col = lane & 15;
    float b1v[8], b2v[8];
#pragma unroll
    for (int t = 0; t < 8; ++t) { b1v[t] = bu1[t * 16 + col]; b2v[t] = bu2[t * 16 + col]; }
    stage_copy<2048, 512>(gW + GW_U1A, sWa, tid);
    stage_copy<2048, 512>(gW + GW_U1B, sWb, tid);
    stage_copy<2048, 512>(gW + GW_U2S, sW2, tid);
    __syncthreads();
    short* myX = &sX[wave][0];
    for (int tile = blockIdx.x * 8 + wave; tile < NN / 16; tile += gridDim.x * 8) {
        const int r0 = tile * 16;
        f32x4 acc1[8];
#pragma unroll
        for (int t = 0; t < 8; ++t) {
            const float b = b1v[t];
            acc1[t] = {b, b, b, b};
        }
#pragma unroll
        for (int s = 0; s < 4; ++s) {
            const bf16x8 ahh = cvt8(&h[(r0 + col) * 128 + s * 32 + q * 8]);
            const bf16x8 aag = cvt8(&agg[(r0 + col) * 128 + s * 32 + q * 8]);
#pragma unroll
            for (int t = 0; t < 8; ++t) {
                const bf16x8 ba = *(const bf16x8*)(sWa + ((s * 8 + t) * 64 + lane) * 8);
                const bf16x8 bb = *(const bf16x8*)(sWb + ((s * 8 + t) * 64 + lane) * 8);
                acc1[t] = __builtin_amdgcn_mfma_f32_16x16x32_bf16(ahh, ba, acc1[t], 0, 0, 0);
                acc1[t] = __builtin_amdgcn_mfma_f32_16x16x32_bf16(aag, bb, acc1[t], 0, 0, 0);
            }
        }
#pragma unroll
        for (int r = 0; r < 4; ++r) {
            bf16x8 vx;
#pragma unroll
            for (int t = 0; t < 8; ++t) {
                const float x = acc1[t][r];
                vx[t] = f2bf(x > 0.f ? x : 0.f);
            }
            *(bf16x8*)(myX + (q * 4 + r) * 136 + col * 8) = vx;
        }
        f32x4 acc2[8];
#pragma unroll
        for (int t = 0; t < 8; ++t) {
            const float b = b2v[t];
#pragma unroll
            for (int r = 0; r < 4; ++r)
                acc2[t][r] = b + h[(r0 + q * 4 + r) * 128 + t * 16 + col];
        }
#pragma unroll
        for (int s = 0; s < 4; ++s) {
            const bf16x8 ax = *(const bf16x8*)(myX + col * 136 + s * 32 + q * 8);
#pragma unroll
            for (int t = 0; t < 8; ++t) {
                const bf16x8 bw = *(const bf16x8*)(sW2 + ((s * 8 + t) * 64 + lane) * 8);
                acc2[t] = __builtin_amdgcn_mfma_f32_16x16x32_bf16(ax, bw, acc2[t], 0, 0, 0);
            }
        }
#pragma unroll
        for (int t = 0; t < 8; ++t)
#pragma unroll
            for (int r = 0; r < 4; ++r)
                out[(r0 + q * 4 + r) * 128 + t * 16 + col] = acc2[t][r];
    }
}

extern "C" void kernel_launch(void* const* d_in, const int* in_sizes, int n_in,
                              void* d_out, int out_size, void* d_ws, size_t ws_size,
                              hipStream_t stream) {
    const float* h   = (const float*)d_in[0];
    const float* ea  = (const float*)d_in[1];
    const float* Wm1 = (const float*)d_in[2];
    const float* bm1 = (const float*)d_in[3];
    const float* Wm2 = (const float*)d_in[4];
    const float* bm2 = (const float*)d_in[5];
    const float* Wu1 = (const float*)d_in[6];
    const float* bu1 = (const float*)d_in[7];
    const float* Wu2 = (const float*)d_in[8];
    const float* bu2 = (const float*)d_in[9];
    const int* eidx  = (const int*)d_in[10];
    float* out = (float*)d_out;

    short* gW  = (short*)d_ws;                       // 102400 shorts
    short* Pb  = gW + GW_TOT;                        // NN*128 bf16
    short* Qb  = Pb + (size_t)NN * 128;              // NN*128 bf16
    float* agg = (float*)(Qb + (size_t)NN * 128);    // NN*128 fp32
    int* cnt    = (int*)(agg + (size_t)NN * 128);    // NN
    int* part   = cnt + NN;                          // NN
    int* bsum   = part + NN;                         // 64
    int* cursor = bsum + 64;                         // NN
    int2* sd2   = (int2*)(cursor + NN);              // NE int2
    short* eb   = (short*)(sd2 + NE);                // NE*32 bf16 (sorted edge attrs)

    const int NB_SCAN = (NN + 1023) / 1024;  // 49
    const int NB_E = (NE + 255) / 256;       // 3125

    hipMemsetAsync(cnt, 0, (size_t)NN * sizeof(int), stream);
    hipMemsetAsync(agg, 0, (size_t)NN * 128 * sizeof(float), stream);
    mega_kernel<<<512 + 50 + NB_E, 256, 0, stream>>>(h, Wm1, bm1, Wm2, Wu1, Wu2,
                                                     eidx, gW, Pb, Qb, cnt);
    scan1_kernel<<<NB_SCAN, 1024, 0, stream>>>(cnt, part, bsum);
    scan23_kernel<<<NB_SCAN, 1024, 0, stream>>>(part, bsum, cursor);
    scatter_kernel<<<NB_E, 256, 0, stream>>>(eidx, cursor, ea, sd2, eb);
    edge_kernel<<<512, 512, 0, stream>>>(Pb, Qb, eb, gW, bm2, sd2, agg);
    update_kernel<<<256, 512, 0, stream>>>(h, agg, gW, bu1, bu2, out);
}

// Round 2
// 598.768 us; speedup vs baseline: 1.0636x; 1.0636x over previous
//
#include <hip/hip_runtime.h>

#define NN 50000
#define NE 800000

typedef __attribute__((ext_vector_type(8))) short bf16x8;
typedef __attribute__((ext_vector_type(4))) float f32x4;

__device__ __forceinline__ short f2bf(float f) {
    union { float f; unsigned u; } v; v.f = f;
    return (short)((v.u + 0x7fffu + ((v.u >> 16) & 1u)) >> 16);
}

__device__ __forceinline__ float bf2f(short s) {
    union { unsigned u; float f; } v;
    v.u = ((unsigned)(unsigned short)s) << 16;
    return v.f;
}

__device__ __forceinline__ bf16x8 cvt8(const float* __restrict__ p) {
    const f32x4 a = *(const f32x4*)p;
    const f32x4 b = *(const f32x4*)(p + 4);
    bf16x8 r;
#pragma unroll
    for (int j = 0; j < 4; ++j) { r[j] = f2bf(a[j]); r[j + 4] = f2bf(b[j]); }
    return r;
}

// gW slot map (slot = 8 shorts at gW + slot*8):
// [0,2048) Wm1a | [2048,4096) Wm1b | [4096,4608) W1c | [4608,6656) Wm2 sigma
// [6656,8704) Wu1a | [8704,10752) Wu1b | [10752,12800) Wu2 sigma
#define GW_M1A 0
#define GW_M1B 16384
#define GW_1C  32768
#define GW_M2S 36864
#define GW_U1A 53248
#define GW_U1B 69632
#define GW_U2S 86016
#define GW_TOT 102400

// Stage W (KROWS x 128 row-major fp32) -> LDS bf16 MFMA B-fragments (node_pq path).
template<int KROWS, int NTHREADS>
__device__ __forceinline__ void stage_w(const float* __restrict__ W, short* lds, int tid) {
    constexpr int NSLOT = (KROWS / 32) * 8 * 64;
#pragma unroll 1
    for (int slot = tid; slot < NSLOT; slot += NTHREADS) {
        const int f = slot >> 6, l = slot & 63;
        const int s = f >> 3, t = f & 7;
        const int k0 = 32 * s + ((l >> 4) << 3);
        const int n = 16 * t + (l & 15);
        bf16x8 v;
#pragma unroll
        for (int j = 0; j < 8; ++j) v[j] = f2bf(W[(k0 + j) * 128 + n]);
        *(bf16x8*)(lds + slot * 8) = v;
    }
}

template<int NSLOT, int NTHREADS>
__device__ __forceinline__ void stage_copy(const short* __restrict__ g, short* lds, int tid) {
#pragma unroll
    for (int i = 0; i < NSLOT / NTHREADS; ++i) {
        const int s = tid + i * NTHREADS;
        *(bf16x8*)(lds + (size_t)s * 8) = *(const bf16x8*)(g + (size_t)s * 8);
    }
}

// ---------------- mega kernel: node_pq (blocks 0..511) | preswz (512..561) | hist (562..) ----------------

__global__ __launch_bounds__(256) void mega_kernel(
    const float* __restrict__ h, const float* __restrict__ Wm1,
    const float* __restrict__ bm1, const float* __restrict__ Wm2,
    const float* __restrict__ Wu1, const float* __restrict__ Wu2,
    const int* __restrict__ eidx, short* __restrict__ gW,
    short* __restrict__ Pb, short* __restrict__ Qb, int* __restrict__ cnt)
{
    const int b = blockIdx.x;
    const int tid = threadIdx.x;
    if (b < 512) {
        // ---- node_pq: P~ = h@Wm1a (sigma bf16), Q~ = h@Wm1b + bm1 ----
        __shared__ short sWa[16384];
        __shared__ short sWb[16384];
        stage_w<128, 256>(Wm1, sWa, tid);
        stage_w<128, 256>(Wm1 + 128 * 128, sWb, tid);
        __syncthreads();
        const int wave = tid >> 6, lane = tid & 63;
        const int q = lane >> 4, col = lane & 15;
        float b1v[8];
#pragma unroll
        for (int t = 0; t < 8; ++t) b1v[t] = bm1[t * 16 + col];
        for (int tile = b * 4 + wave; tile < NN / 16; tile += 2048) {
            const int r0 = tile * 16;
            f32x4 aP[8], aQ[8];
#pragma unroll
            for (int t = 0; t < 8; ++t) {
                aP[t] = {0.f, 0.f, 0.f, 0.f};
                const float bb = b1v[t];
                aQ[t] = {bb, bb, bb, bb};
            }
#pragma unroll
            for (int s = 0; s < 4; ++s) {
                const bf16x8 ah = cvt8(&h[(r0 + col) * 128 + s * 32 + q * 8]);
#pragma unroll
                for (int t = 0; t < 8; ++t) {
                    const bf16x8 ba = *(const bf16x8*)(sWa + ((s * 8 + t) * 64 + lane) * 8);
                    const bf16x8 bb = *(const bf16x8*)(sWb + ((s * 8 + t) * 64 + lane) * 8);
                    aP[t] = __builtin_amdgcn_mfma_f32_16x16x32_bf16(ah, ba, aP[t], 0, 0, 0);
                    aQ[t] = __builtin_amdgcn_mfma_f32_16x16x32_bf16(ah, bb, aQ[t], 0, 0, 0);
                }
            }
#pragma unroll
            for (int r = 0; r < 4; ++r) {
                const size_t row = (size_t)(r0 + q * 4 + r) * 128;
                bf16x8 vp, vq;
#pragma unroll
                for (int t = 0; t < 8; ++t) { vp[t] = f2bf(aP[t][r]); vq[t] = f2bf(aQ[t][r]); }
                *(bf16x8*)(Pb + row + col * 8) = vp;
                *(bf16x8*)(Qb + row + col * 8) = vq;
            }
        }
    } else if (b < 562) {
        // ---- preswz: weights -> global bf16 fragments ----
        const int slot = (b - 512) * 256 + tid;
        if (slot < 12800) {
            const float* W; int local; bool sigma = false;
            if (slot < 2048)       { W = Wm1;             local = slot; }
            else if (slot < 4096)  { W = Wm1 + 128 * 128; local = slot - 2048; }
            else if (slot < 4608)  { W = Wm1 + 256 * 128; local = slot - 4096; }
            else if (slot < 6656)  { W = Wm2;             local = slot - 4608; sigma = true; }
            else if (slot < 8704)  { W = Wu1;             local = slot - 6656; }
            else if (slot < 10752) { W = Wu1 + 128 * 128; local = slot - 8704; }
            else                   { W = Wu2;             local = slot - 10752; sigma = true; }
            const int f = local >> 6, l = local & 63;
            const int s = f >> 3, t = f & 7;
            const int k0 = 32 * s + ((l >> 4) << 3);
            const int n = 16 * t + (l & 15);
            bf16x8 v;
#pragma unroll
            for (int j = 0; j < 8; ++j) {
                int k = k0 + j;
                if (sigma) k = (k & 7) * 16 + (k >> 3);
                v[j] = f2bf(W[k * 128 + n]);
            }
            *(bf16x8*)(gW + (size_t)slot * 8) = v;
        }
    } else {
        // ---- hist ----
        const int e = (b - 562) * 256 + tid;
        if (e < NE) atomicAdd(&cnt[eidx[NE + e]], 1);
    }
}

// ---------------- scan ----------------

__global__ __launch_bounds__(1024) void scan1_kernel(const int* __restrict__ cnt,
                                                     int* __restrict__ part,
                                                     int* __restrict__ bsum) {
    __shared__ int s[1024];
    const int t = threadIdx.x;
    const int i = blockIdx.x * 1024 + t;
    const int v = (i < NN) ? cnt[i] : 0;
    int x = v;
    s[t] = x;
    __syncthreads();
    for (int off = 1; off < 1024; off <<= 1) {
        const int y = (t >= off) ? s[t - off] : 0;
        __syncthreads();
        x += y;
        s[t] = x;
        __syncthreads();
    }
    if (i < NN) part[i] = x - v;
    if (t == 1023) bsum[blockIdx.x] = x;
}

__global__ __launch_bounds__(1024) void scan23_kernel(const int* __restrict__ part,
                                                      const int* __restrict__ bsum,
                                                      int* __restrict__ cursor) {
    __shared__ int off;
    if (threadIdx.x == 0) {
        int a = 0;
        for (int bb = 0; bb < (int)blockIdx.x; ++bb) a += bsum[bb];
        off = a;
    }
    __syncthreads();
    const int i = blockIdx.x * 1024 + threadIdx.x;
    if (i < NN) cursor[i] = part[i] + off;
}

// ---------------- scatter: perm edges to sorted order; also permute+cvt ea -> eb (bf16) ----------------

__global__ void scatter_kernel(const int* __restrict__ eidx, int* __restrict__ cursor,
                               const float* __restrict__ ea,
                               int2* __restrict__ sd2, short* __restrict__ eb) {
    const int e = blockIdx.x * blockDim.x + threadIdx.x;
    if (e < NE) {
        const int d = eidx[NE + e];
        const int pos = atomicAdd(&cursor[d], 1);
        sd2[pos] = make_int2(eidx[e], d);
        const float* src = ea + (size_t)e * 32;
        short* dst = eb + (size_t)pos * 32;
#pragma unroll
        for (int j = 0; j < 4; ++j) {
            const f32x4 a = *(const f32x4*)(src + j * 8);
            const f32x4 bq = *(const f32x4*)(src + j * 8 + 4);
            bf16x8 v;
#pragma unroll
            for (int k = 0; k < 4; ++k) { v[k] = f2bf(a[k]); v[4 + k] = f2bf(bq[k]); }
            *(bf16x8*)(dst + j * 8) = v;
        }
    }
}

// ---------------- edge kernel: dst-sorted tiles, segmented reduce, cross-tile pipelined ----------------
// Round-1 post-mortem: pipeline state was SPILLED (VGPR pinned at 128 by the allocator's
// LDS-derived occupancy target of 4 waves/EU; scratch churn = +136MB FETCH). Fix: pad sX
// pitch 136->168 so block LDS = 83968B > 81920 -> 1 block/CU -> LDS-implied occupancy
// 2 waves/EU -> VGPR budget 256 -> pipeline state stays in registers. Grid 256 blocks
// (exact residency, ~24 tiles/wave). Verify via VGPR_Count>128 and FETCH ~145MB.
#define XSTR 168

__global__ __launch_bounds__(512, 2) void edge_kernel(
    const short* __restrict__ Pb, const short* __restrict__ Qb,
    const short* __restrict__ eb, const short* __restrict__ gW,
    const float* __restrict__ bm2,
    const int2* __restrict__ sd2, float* __restrict__ agg)
{
    __shared__ short sW2[16384];
    __shared__ short sW1c[4096];
    __shared__ short sX[8][16 * XSTR];
    const int tid = threadIdx.x;
    const int wave = tid >> 6, lane = tid & 63;
    const int q = lane >> 4, col = lane & 15;
    const int NT = NE / 16;
    const int STR = gridDim.x * 8;
    const int tile0 = blockIdx.x * 8 + wave;
    float b2v[8];
#pragma unroll
    for (int t = 0; t < 8; ++t) b2v[t] = bm2[t * 16 + col];

    // prologue: issue first sd2 load, stage weights (hides sd latency), then first gathers
    int2 sd_c[4];
    {
        const int e0 = tile0 * 16;
        const int4 a0 = *(const int4*)(sd2 + e0 + q * 4);
        const int4 a1 = *(const int4*)(sd2 + e0 + q * 4 + 2);
        sd_c[0] = make_int2(a0.x, a0.y); sd_c[1] = make_int2(a0.z, a0.w);
        sd_c[2] = make_int2(a1.x, a1.y); sd_c[3] = make_int2(a1.z, a1.w);
    }
    stage_copy<2048, 512>(gW + GW_M2S, sW2, tid);
    stage_copy<512, 512>(gW + GW_1C, sW1c, tid);
    bf16x8 vp[4], vq[4], aea;
#pragma unroll
    for (int r = 0; r < 4; ++r) {
        vp[r] = *(const bf16x8*)(Pb + (size_t)sd_c[r].x * 128 + col * 8);
        vq[r] = *(const bf16x8*)(Qb + (size_t)sd_c[r].y * 128 + col * 8);
    }
    aea = *(const bf16x8*)(eb + (size_t)(tile0 * 16 + col) * 32 + q * 8);
    __syncthreads();
    short* myX = &sX[wave][0];

    for (int tile = tile0; tile < NT; tile += STR) {
        // next tile index (clamped: last iteration harmlessly re-reads current tile)
        const int tn = (tile + STR < NT) ? (tile + STR) : tile;
        // run-structure mask for current tile
        const int prev3 = __shfl_up(sd_c[3].y, 16);
        unsigned qm = 0;
        if (q > 0 && sd_c[0].y == prev3) qm |= 1u;
        if (sd_c[1].y == sd_c[0].y) qm |= 2u;
        if (sd_c[2].y == sd_c[1].y) qm |= 4u;
        if (sd_c[3].y == sd_c[2].y) qm |= 8u;
        const unsigned o1 = (unsigned)__shfl_xor((int)qm, 16);
        const unsigned o2 = (unsigned)__shfl_xor((int)qm, 32);
        const unsigned o3 = (unsigned)__shfl_xor((int)o1, 32);
        const unsigned eqmask = (qm << (q * 4)) | (o1 << ((q ^ 1) * 4)) |
                                (o2 << ((q ^ 2) * 4)) | (o3 << ((q ^ 3) * 4));
        // issue next-tile sd2 load (latency hidden under layer1 + X)
        int2 sd_n[4];
        {
            const int en = tn * 16;
            const int4 a0 = *(const int4*)(sd2 + en + q * 4);
            const int4 a1 = *(const int4*)(sd2 + en + q * 4 + 2);
            sd_n[0] = make_int2(a0.x, a0.y); sd_n[1] = make_int2(a0.z, a0.w);
            sd_n[2] = make_int2(a1.x, a1.y); sd_n[3] = make_int2(a1.z, a1.w);
        }
        // layer 1: gathered P~[src] + Q~[dst](+b1)  (vp/vq prefetched last iteration)
        f32x4 acc1[8];
#pragma unroll
        for (int r = 0; r < 4; ++r) {
            const bf16x8 vpr = vp[r], vqr = vq[r];
#pragma unroll
            for (int t = 0; t < 8; ++t)
                acc1[t][r] = bf2f(vpr[t]) + bf2f(vqr[t]);
        }
        // + ea @ W1c
#pragma unroll
        for (int t = 0; t < 8; ++t) {
            const bf16x8 bw = *(const bf16x8*)(sW1c + (t * 64 + lane) * 8);
            acc1[t] = __builtin_amdgcn_mfma_f32_16x16x32_bf16(aea, bw, acc1[t], 0, 0, 0);
        }
        // relu -> bf16 -> X~ LDS
#pragma unroll
        for (int r = 0; r < 4; ++r) {
            bf16x8 vx;
#pragma unroll
            for (int t = 0; t < 8; ++t) {
                const float x = acc1[t][r];
                vx[t] = f2bf(x > 0.f ? x : 0.f);
            }
            *(bf16x8*)(myX + (q * 4 + r) * XSTR + col * 8) = vx;
        }
        // layer 2, first half (s=0,1)
        f32x4 acc2[8];
#pragma unroll
        for (int t = 0; t < 8; ++t) {
            const float b = b2v[t];
            acc2[t] = {b, b, b, b};
        }
#pragma unroll
        for (int s = 0; s < 2; ++s) {
            const bf16x8 ax = *(const bf16x8*)(myX + col * XSTR + s * 32 + q * 8);
#pragma unroll
            for (int t = 0; t < 8; ++t) {
                const bf16x8 bw = *(const bf16x8*)(sW2 + ((s * 8 + t) * 64 + lane) * 8);
                acc2[t] = __builtin_amdgcn_mfma_f32_16x16x32_bf16(ax, bw, acc2[t], 0, 0, 0);
            }
        }
        // prefetch next-tile gathers (old vp/vq/aea dead since layer1; consumed next iter —
        // latency hidden under layer2 second half + reduce + next masks)
#pragma unroll
        for (int r = 0; r < 4; ++r) {
            vp[r] = *(const bf16x8*)(Pb + (size_t)sd_n[r].x * 128 + col * 8);
            vq[r] = *(const bf16x8*)(Qb + (size_t)sd_n[r].y * 128 + col * 8);
        }
        aea = *(const bf16x8*)(eb + (size_t)(tn * 16 + col) * 32 + q * 8);
        // layer 2, second half (s=2,3)
#pragma unroll
        for (int s = 2; s < 4; ++s) {
            const bf16x8 ax = *(const bf16x8*)(myX + col * XSTR + s * 32 + q * 8);
#pragma unroll
            for (int t = 0; t < 8; ++t) {
                const bf16x8 bw = *(const bf16x8*)(sW2 + ((s * 8 + t) * 64 + lane) * 8);
                acc2[t] = __builtin_amdgcn_mfma_f32_16x16x32_bf16(ax, bw, acc2[t], 0, 0, 0);
            }
        }
        // segmented reduce + atomics
        if (eqmask == 0xFFFEu) {
#pragma unroll
            for (int t = 0; t < 8; ++t) {
                float m0 = acc2[t][0]; m0 = m0 > 0.f ? m0 : 0.f;
                float m1 = acc2[t][1]; m1 = m1 > 0.f ? m1 : 0.f;
                float m2 = acc2[t][2]; m2 = m2 > 0.f ? m2 : 0.f;
                float m3 = acc2[t][3]; m3 = m3 > 0.f ? m3 : 0.f;
                float s = (m0 + m1) + (m2 + m3);
                s += __shfl_xor(s, 16);
                s += __shfl_xor(s, 32);
                if (q == 0 && s != 0.f)
                    unsafeAtomicAdd(&agg[(size_t)sd_c[0].y * 128 + t * 16 + col], s);
            }
        } else {
            int head[4], qe[4];
#pragma unroll
            for (int r = 0; r < 4; ++r) {
                const int e = q * 4 + r;
                head[r] = !((eqmask >> e) & 1u);
                const unsigned after = ~(eqmask >> (e + 1));
                const int run = __builtin_ctz(after);
                qe[r] = (e + run) >> 2;
            }
#pragma unroll
            for (int t = 0; t < 8; ++t) {
                float m0 = acc2[t][0]; m0 = m0 > 0.f ? m0 : 0.f;
                float m1 = acc2[t][1]; m1 = m1 > 0.f ? m1 : 0.f;
                float m2 = acc2[t][2]; m2 = m2 > 0.f ? m2 : 0.f;
                float m3 = acc2[t][3]; m3 = m3 > 0.f ? m3 : 0.f;
                const float s3 = m3;
                const float s2 = m2 + ((qm & 8u) ? s3 : 0.f);
                const float s1 = m1 + ((qm & 4u) ? s2 : 0.f);
                const float s0 = m0 + ((qm & 2u) ? s1 : 0.f);
                const float p1 = __shfl_xor(s0, 16);
                const float p2 = __shfl_xor(s0, 32);
                const float p3 = __shfl_xor(p1, 32);
                const float seg[4] = {s0, s1, s2, s3};
#pragma unroll
                for (int r = 0; r < 4; ++r) {
                    if (head[r]) {
                        float tot = seg[r];
#pragma unroll
                        for (int j = 1; j < 4; ++j) {
                            if (j > q && j <= qe[r]) {
                                const int jx = j ^ q;
                                tot += (jx == 1) ? p1 : (jx == 2) ? p2 : p3;
                            }
                        }
                        if (tot != 0.f)
                            unsafeAtomicAdd(&agg[(size_t)sd_c[r].y * 128 + t * 16 + col], tot);
                    }
                }
            }
        }
        // rotate pipeline state
#pragma unroll
        for (int r = 0; r < 4; ++r) sd_c[r] = sd_n[r];
    }
}

// ---------------- update MLP + residual ----------------

__global__ __launch_bounds__(512) void update_kernel(
    const float* __restrict__ h, const float* __restrict__ agg,
    const short* __restrict__ gW, const float* __restrict__ bu1,
    const float* __restrict__ bu2, float* __restrict__ out)
{
    __shared__ short sWa[16384];
    __shared__ short sWb[16384];
    __shared__ short sW2[16384];
    __shared__ short sX[8][16 * 136];
    const int tid = threadIdx.x;
    const int wave = tid >> 6, lane = tid & 63;
    const int q = lane >> 4, col = lane & 15;
    float b1v[8], b2v[8];
#pragma unroll
    for (int t = 0; t < 8; ++t) { b1v[t] = bu1[t * 16 + col]; b2v[t] = bu2[t * 16 + col]; }
    stage_copy<2048, 512>(gW + GW_U1A, sWa, tid);
    stage_copy<2048, 512>(gW + GW_U1B, sWb, tid);
    stage_copy<2048, 512>(gW + GW_U2S, sW2, tid);
    __syncthreads();
    short* myX = &sX[wave][0];
    for (int tile = blockIdx.x * 8 + wave; tile < NN / 16; tile += gridDim.x * 8) {
        const int r0 = tile * 16;
        f32x4 acc1[8];
#pragma unroll
        for (int t = 0; t < 8; ++t) {
            const float b = b1v[t];
            acc1[t] = {b, b, b, b};
        }
#pragma unroll
        for (int s = 0; s < 4; ++s) {
            const bf16x8 ahh = cvt8(&h[(r0 + col) * 128 + s * 32 + q * 8]);
            const bf16x8 aag = cvt8(&agg[(r0 + col) * 128 + s * 32 + q * 8]);
#pragma unroll
            for (int t = 0; t < 8; ++t) {
                const bf16x8 ba = *(const bf16x8*)(sWa + ((s * 8 + t) * 64 + lane) * 8);
                const bf16x8 bb = *(const bf16x8*)(sWb + ((s * 8 + t) * 64 + lane) * 8);
                acc1[t] = __builtin_amdgcn_mfma_f32_16x16x32_bf16(ahh, ba, acc1[t], 0, 0, 0);
                acc1[t] = __builtin_amdgcn_mfma_f32_16x16x32_bf16(aag, bb, acc1[t], 0, 0, 0);
            }
        }
#pragma unroll
        for (int r = 0; r < 4; ++r) {
            bf16x8 vx;
#pragma unroll
            for (int t = 0; t < 8; ++t) {
                const float x = acc1[t][r];
                vx[t] = f2bf(x > 0.f ? x : 0.f);
            }
            *(bf16x8*)(myX + (q * 4 + r) * 136 + col * 8) = vx;
        }
        f32x4 acc2[8];
#pragma unroll
        for (int t = 0; t < 8; ++t) {
            const float b = b2v[t];
#pragma unroll
            for (int r = 0; r < 4; ++r)
                acc2[t][r] = b + h[(r0 + q * 4 + r) * 128 + t * 16 + col];
        }
#pragma unroll
        for (int s = 0; s < 4; ++s) {
            const bf16x8 ax = *(const bf16x8*)(myX + col * 136 + s * 32 + q * 8);
#pragma unroll
            for (int t = 0; t < 8; ++t) {
                const bf16x8 bw = *(const bf16x8*)(sW2 + ((s * 8 + t) * 64 + lane) * 8);
                acc2[t] = __builtin_amdgcn_mfma_f32_16x16x32_bf16(ax, bw, acc2[t], 0, 0, 0);
            }
        }
#pragma unroll
        for (int t = 0; t < 8; ++t)
#pragma unroll
            for (int r = 0; r < 4; ++r)
                out[(r0 + q * 4 + r) * 128 + t * 16 + col] = acc2[t][r];
    }
}

extern "C" void kernel_launch(void* const* d_in, const int* in_sizes, int n_in,
                              void* d_out, int out_size, void* d_ws, size_t ws_size,
                              hipStream_t stream) {
    const float* h   = (const float*)d_in[0];
    const float* ea  = (const float*)d_in[1];
    const float* Wm1 = (const float*)d_in[2];
    const float* bm1 = (const float*)d_in[3];
    const float* Wm2 = (const float*)d_in[4];
    const float* bm2 = (const float*)d_in[5];
    const float* Wu1 = (const float*)d_in[6];
    const float* bu1 = (const float*)d_in[7];
    const float* Wu2 = (const float*)d_in[8];
    const float* bu2 = (const float*)d_in[9];
    const int* eidx  = (const int*)d_in[10];
    float* out = (float*)d_out;

    short* gW  = (short*)d_ws;                       // 102400 shorts
    short* Pb  = gW + GW_TOT;                        // NN*128 bf16
    short* Qb  = Pb + (size_t)NN * 128;              // NN*128 bf16
    float* agg = (float*)(Qb + (size_t)NN * 128);    // NN*128 fp32
    int* cnt    = (int*)(agg + (size_t)NN * 128);    // NN
    int* part   = cnt + NN;                          // NN
    int* bsum   = part + NN;                         // 64
    int* cursor = bsum + 64;                         // NN
    int2* sd2   = (int2*)(cursor + NN);              // NE int2
    short* eb   = (short*)(sd2 + NE);                // NE*32 bf16 (sorted edge attrs)

    const int NB_SCAN = (NN + 1023) / 1024;  // 49
    const int NB_E = (NE + 255) / 256;       // 3125

    hipMemsetAsync(cnt, 0, (size_t)NN * sizeof(int), stream);
    hipMemsetAsync(agg, 0, (size_t)NN * 128 * sizeof(float), stream);
    mega_kernel<<<512 + 50 + NB_E, 256, 0, stream>>>(h, Wm1, bm1, Wm2, Wu1, Wu2,
                                                     eidx, gW, Pb, Qb, cnt);
    scan1_kernel<<<NB_SCAN, 1024, 0, stream>>>(cnt, part, bsum);
    scan23_kernel<<<NB_SCAN, 1024, 0, stream>>>(part, bsum, cursor);
    scatter_kernel<<<NB_E, 256, 0, stream>>>(eidx, cursor, ea, sd2, eb);
    edge_kernel<<<256, 512, 0, stream>>>(Pb, Qb, eb, gW, bm2, sd2, agg);
    update_kernel<<<256, 512, 0, stream>>>(h, agg, gW, bu1, bu2, out);
}

// Round 3
// 570.305 us; speedup vs baseline: 1.1167x; 1.0499x over previous
//
#include <hip/hip_runtime.h>

#define NN 50000
#define NE 800000

typedef __attribute__((ext_vector_type(8))) short bf16x8;
typedef __attribute__((ext_vector_type(4))) float f32x4;

__device__ __forceinline__ short f2bf(float f) {
    union { float f; unsigned u; } v; v.f = f;
    return (short)((v.u + 0x7fffu + ((v.u >> 16) & 1u)) >> 16);
}

__device__ __forceinline__ float bf2f(short s) {
    union { unsigned u; float f; } v;
    v.u = ((unsigned)(unsigned short)s) << 16;
    return v.f;
}

__device__ __forceinline__ bf16x8 cvt8(const float* __restrict__ p) {
    const f32x4 a = *(const f32x4*)p;
    const f32x4 b = *(const f32x4*)(p + 4);
    bf16x8 r;
#pragma unroll
    for (int j = 0; j < 4; ++j) { r[j] = f2bf(a[j]); r[j + 4] = f2bf(b[j]); }
    return r;
}

// Async global->LDS DMA, 16B per lane: per-lane global addr, wave-uniform LDS base;
// HW writes lane i's data at base + i*16. Tracked by vmcnt. Cannot be sunk/remat'd
// by the compiler (rounds 1-2 showed register prefetch gets rematerialized at use).
__device__ __forceinline__ void gld_lds16(const short* g, short* l) {
    __builtin_amdgcn_global_load_lds(
        (const __attribute__((address_space(1))) void*)g,
        (__attribute__((address_space(3))) void*)l, 16, 0, 0);
}

// gW slot map (slot = 8 shorts at gW + slot*8):
// [0,2048) Wm1a | [2048,4096) Wm1b | [4096,4608) W1c | [4608,6656) Wm2 sigma
// [6656,8704) Wu1a | [8704,10752) Wu1b | [10752,12800) Wu2 sigma
#define GW_M1A 0
#define GW_M1B 16384
#define GW_1C  32768
#define GW_M2S 36864
#define GW_U1A 53248
#define GW_U1B 69632
#define GW_U2S 86016
#define GW_TOT 102400

// Stage W (KROWS x 128 row-major fp32) -> LDS bf16 MFMA B-fragments (node_pq path).
template<int KROWS, int NTHREADS>
__device__ __forceinline__ void stage_w(const float* __restrict__ W, short* lds, int tid) {
    constexpr int NSLOT = (KROWS / 32) * 8 * 64;
#pragma unroll 1
    for (int slot = tid; slot < NSLOT; slot += NTHREADS) {
        const int f = slot >> 6, l = slot & 63;
        const int s = f >> 3, t = f & 7;
        const int k0 = 32 * s + ((l >> 4) << 3);
        const int n = 16 * t + (l & 15);
        bf16x8 v;
#pragma unroll
        for (int j = 0; j < 8; ++j) v[j] = f2bf(W[(k0 + j) * 128 + n]);
        *(bf16x8*)(lds + slot * 8) = v;
    }
}

template<int NSLOT, int NTHREADS>
__device__ __forceinline__ void stage_copy(const short* __restrict__ g, short* lds, int tid) {
#pragma unroll 1
    for (int s = tid; s < NSLOT; s += NTHREADS) {
        *(bf16x8*)(lds + (size_t)s * 8) = *(const bf16x8*)(g + (size_t)s * 8);
    }
}

// ---------------- mega kernel: node_pq (blocks 0..511) | preswz (512..561) | hist (562..) ----------------

__global__ __launch_bounds__(256) void mega_kernel(
    const float* __restrict__ h, const float* __restrict__ Wm1,
    const float* __restrict__ bm1, const float* __restrict__ Wm2,
    const float* __restrict__ Wu1, const float* __restrict__ Wu2,
    const int* __restrict__ eidx, short* __restrict__ gW,
    short* __restrict__ Pb, short* __restrict__ Qb, int* __restrict__ cnt)
{
    const int b = blockIdx.x;
    const int tid = threadIdx.x;
    if (b < 512) {
        // ---- node_pq: P~ = h@Wm1a (sigma bf16), Q~ = h@Wm1b + bm1 ----
        __shared__ short sWa[16384];
        __shared__ short sWb[16384];
        stage_w<128, 256>(Wm1, sWa, tid);
        stage_w<128, 256>(Wm1 + 128 * 128, sWb, tid);
        __syncthreads();
        const int wave = tid >> 6, lane = tid & 63;
        const int q = lane >> 4, col = lane & 15;
        float b1v[8];
#pragma unroll
        for (int t = 0; t < 8; ++t) b1v[t] = bm1[t * 16 + col];
        for (int tile = b * 4 + wave; tile < NN / 16; tile += 2048) {
            const int r0 = tile * 16;
            f32x4 aP[8], aQ[8];
#pragma unroll
            for (int t = 0; t < 8; ++t) {
                aP[t] = {0.f, 0.f, 0.f, 0.f};
                const float bb = b1v[t];
                aQ[t] = {bb, bb, bb, bb};
            }
#pragma unroll
            for (int s = 0; s < 4; ++s) {
                const bf16x8 ah = cvt8(&h[(r0 + col) * 128 + s * 32 + q * 8]);
#pragma unroll
                for (int t = 0; t < 8; ++t) {
                    const bf16x8 ba = *(const bf16x8*)(sWa + ((s * 8 + t) * 64 + lane) * 8);
                    const bf16x8 bb = *(const bf16x8*)(sWb + ((s * 8 + t) * 64 + lane) * 8);
                    aP[t] = __builtin_amdgcn_mfma_f32_16x16x32_bf16(ah, ba, aP[t], 0, 0, 0);
                    aQ[t] = __builtin_amdgcn_mfma_f32_16x16x32_bf16(ah, bb, aQ[t], 0, 0, 0);
                }
            }
#pragma unroll
            for (int r = 0; r < 4; ++r) {
                const size_t row = (size_t)(r0 + q * 4 + r) * 128;
                bf16x8 vp, vq;
#pragma unroll
                for (int t = 0; t < 8; ++t) { vp[t] = f2bf(aP[t][r]); vq[t] = f2bf(aQ[t][r]); }
                *(bf16x8*)(Pb + row + col * 8) = vp;
                *(bf16x8*)(Qb + row + col * 8) = vq;
            }
        }
    } else if (b < 562) {
        // ---- preswz: weights -> global bf16 fragments ----
        const int slot = (b - 512) * 256 + tid;
        if (slot < 12800) {
            const float* W; int local; bool sigma = false;
            if (slot < 2048)       { W = Wm1;             local = slot; }
            else if (slot < 4096)  { W = Wm1 + 128 * 128; local = slot - 2048; }
            else if (slot < 4608)  { W = Wm1 + 256 * 128; local = slot - 4096; }
            else if (slot < 6656)  { W = Wm2;             local = slot - 4608; sigma = true; }
            else if (slot < 8704)  { W = Wu1;             local = slot - 6656; }
            else if (slot < 10752) { W = Wu1 + 128 * 128; local = slot - 8704; }
            else                   { W = Wu2;             local = slot - 10752; sigma = true; }
            const int f = local >> 6, l = local & 63;
            const int s = f >> 3, t = f & 7;
            const int k0 = 32 * s + ((l >> 4) << 3);
            const int n = 16 * t + (l & 15);
            bf16x8 v;
#pragma unroll
            for (int j = 0; j < 8; ++j) {
                int k = k0 + j;
                if (sigma) k = (k & 7) * 16 + (k >> 3);
                v[j] = f2bf(W[k * 128 + n]);
            }
            *(bf16x8*)(gW + (size_t)slot * 8) = v;
        }
    } else {
        // ---- hist ----
        const int e = (b - 562) * 256 + tid;
        if (e < NE) atomicAdd(&cnt[eidx[NE + e]], 1);
    }
}

// ---------------- scan ----------------

__global__ __launch_bounds__(1024) void scan1_kernel(const int* __restrict__ cnt,
                                                     int* __restrict__ part,
                                                     int* __restrict__ bsum) {
    __shared__ int s[1024];
    const int t = threadIdx.x;
    const int i = blockIdx.x * 1024 + t;
    const int v = (i < NN) ? cnt[i] : 0;
    int x = v;
    s[t] = x;
    __syncthreads();
    for (int off = 1; off < 1024; off <<= 1) {
        const int y = (t >= off) ? s[t - off] : 0;
        __syncthreads();
        x += y;
        s[t] = x;
        __syncthreads();
    }
    if (i < NN) part[i] = x - v;
    if (t == 1023) bsum[blockIdx.x] = x;
}

__global__ __launch_bounds__(1024) void scan23_kernel(const int* __restrict__ part,
                                                      const int* __restrict__ bsum,
                                                      int* __restrict__ cursor) {
    __shared__ int off;
    if (threadIdx.x == 0) {
        int a = 0;
        for (int bb = 0; bb < (int)blockIdx.x; ++bb) a += bsum[bb];
        off = a;
    }
    __syncthreads();
    const int i = blockIdx.x * 1024 + threadIdx.x;
    if (i < NN) cursor[i] = part[i] + off;
}

// ---------------- scatter: perm edges to sorted order; also permute+cvt ea -> eb (bf16) ----------------

__global__ void scatter_kernel(const int* __restrict__ eidx, int* __restrict__ cursor,
                               const float* __restrict__ ea,
                               int2* __restrict__ sd2, short* __restrict__ eb) {
    const int e = blockIdx.x * blockDim.x + threadIdx.x;
    if (e < NE) {
        const int d = eidx[NE + e];
        const int pos = atomicAdd(&cursor[d], 1);
        sd2[pos] = make_int2(eidx[e], d);
        const float* src = ea + (size_t)e * 32;
        short* dst = eb + (size_t)pos * 32;
#pragma unroll
        for (int j = 0; j < 4; ++j) {
            const f32x4 a = *(const f32x4*)(src + j * 8);
            const f32x4 bq = *(const f32x4*)(src + j * 8 + 4);
            bf16x8 v;
#pragma unroll
            for (int k = 0; k < 4; ++k) { v[k] = f2bf(a[k]); v[4 + k] = f2bf(bq[k]); }
            *(bf16x8*)(dst + j * 8) = v;
        }
    }
}

// ---------------- edge kernel: chunked tiles + LDS-DMA double-buffered gather pipeline ----
// Rounds 1-2 post-mortem: register prefetch of P/Q gathers gets REMATERIALIZED by the
// compiler at the 128-VGPR cap (VGPR=128, +120MB FETCH from doubled gathers, no hiding).
// Fix: prefetch via __builtin_amdgcn_global_load_lds into a per-wave LDS double buffer
// (DMA can't be sunk/remat'd; state lives in LDS, not VGPRs). asm s_waitcnt vmcnt(0) at
// iter top: issue-to-wait distance = one full compute phase -> near-free wait.
// Chunked tile assignment (28 consecutive tiles/wave) makes eb/sd2/Qb streams sequential.
// LDS: sW2 32K + sW1c 8K + 7 waves x 2 x 8K (P 4K + Q 4K; X~ overlays consumed cur-buf)
// = 152KB -> 448 thr (7 waves), 1 block/CU, 256 blocks.
#define WPB 7
#define TPW 28  // ceil(50000 / (256*7))

__global__ __launch_bounds__(448, 2) void edge_kernel(
    const short* __restrict__ Pb, const short* __restrict__ Qb,
    const short* __restrict__ eb, const short* __restrict__ gW,
    const float* __restrict__ bm2,
    const int2* __restrict__ sd2, float* __restrict__ agg)
{
    __shared__ short sW2[16384];
    __shared__ short sW1c[4096];
    __shared__ short sPool[WPB][2][4096];
    const int tid = threadIdx.x;
    const int wave = tid >> 6, lane = tid & 63;
    const int q = lane >> 4, col = lane & 15;
    const int NT = NE / 16;
    float b2v[8];
#pragma unroll
    for (int t = 0; t < 8; ++t) b2v[t] = bm2[t * 16 + col];
    stage_copy<2048, 448>(gW + GW_M2S, sW2, tid);
    stage_copy<512, 448>(gW + GW_1C, sW1c, tid);

    const int wg = blockIdx.x * WPB + wave;
    const int t_begin = wg * TPW;
    const int t_end = (t_begin + TPW < NT) ? (t_begin + TPW) : NT;
    const bool act = t_begin < t_end;

    short* bufc = &sPool[wave][0][0];
    short* bufa = &sPool[wave][1][0];
    int2 sd_c[4], sd_n[4];
    bf16x8 aea_c;

    if (act) {
        // prologue: sd[t0] -> stage tile t0 into buf0; sd[t0+1]; aea[t0]
        {
            const int e0 = t_begin * 16;
            const int4 a0 = *(const int4*)(sd2 + e0 + q * 4);
            const int4 a1 = *(const int4*)(sd2 + e0 + q * 4 + 2);
            sd_c[0] = make_int2(a0.x, a0.y); sd_c[1] = make_int2(a0.z, a0.w);
            sd_c[2] = make_int2(a1.x, a1.y); sd_c[3] = make_int2(a1.z, a1.w);
        }
#pragma unroll
        for (int r = 0; r < 4; ++r) {
            gld_lds16(Pb + (size_t)sd_c[r].x * 128 + col * 8, bufc + r * 512);
            gld_lds16(Qb + (size_t)sd_c[r].y * 128 + col * 8, bufc + 2048 + r * 512);
        }
        {
            const int t1 = (t_begin + 1 < t_end) ? t_begin + 1 : t_begin;
            const int e1 = t1 * 16;
            const int4 a0 = *(const int4*)(sd2 + e1 + q * 4);
            const int4 a1 = *(const int4*)(sd2 + e1 + q * 4 + 2);
            sd_n[0] = make_int2(a0.x, a0.y); sd_n[1] = make_int2(a0.z, a0.w);
            sd_n[2] = make_int2(a1.x, a1.y); sd_n[3] = make_int2(a1.z, a1.w);
        }
        aea_c = *(const bf16x8*)(eb + (size_t)(t_begin * 16 + col) * 32 + q * 8);
    }
    __syncthreads();

    for (int tile = t_begin; tile < t_end; ++tile) {
        const int tn = (tile + 1 < t_end) ? tile + 1 : tile;
        // wait: cur-buffer staging (issued one full compute phase ago) complete
        asm volatile("s_waitcnt vmcnt(0)" ::: "memory");
        // consume staged gathers (conflict-free ds_read_b128 at lane*16)
        bf16x8 vp[4], vq[4];
#pragma unroll
        for (int r = 0; r < 4; ++r) {
            vp[r] = *(const bf16x8*)(bufc + r * 512 + lane * 8);
            vq[r] = *(const bf16x8*)(bufc + 2048 + r * 512 + lane * 8);
        }
        // issue next-tile staging into alt buffer (latency spans whole iteration)
#pragma unroll
        for (int r = 0; r < 4; ++r) {
            gld_lds16(Pb + (size_t)sd_n[r].x * 128 + col * 8, bufa + r * 512);
            gld_lds16(Qb + (size_t)sd_n[r].y * 128 + col * 8, bufa + 2048 + r * 512);
        }
        // register-prefetch next aea (streamed, chunked) and sd[tile+2]
        const bf16x8 aea_n = *(const bf16x8*)(eb + (size_t)(tn * 16 + col) * 32 + q * 8);
        int2 sd_n2[4];
        {
            const int t2 = (tile + 2 < t_end) ? tile + 2 : t_end - 1;
            const int e2 = t2 * 16;
            const int4 a0 = *(const int4*)(sd2 + e2 + q * 4);
            const int4 a1 = *(const int4*)(sd2 + e2 + q * 4 + 2);
            sd_n2[0] = make_int2(a0.x, a0.y); sd_n2[1] = make_int2(a0.z, a0.w);
            sd_n2[2] = make_int2(a1.x, a1.y); sd_n2[3] = make_int2(a1.z, a1.w);
        }
        // run-structure mask for current tile
        const int prev3 = __shfl_up(sd_c[3].y, 16);
        unsigned qm = 0;
        if (q > 0 && sd_c[0].y == prev3) qm |= 1u;
        if (sd_c[1].y == sd_c[0].y) qm |= 2u;
        if (sd_c[2].y == sd_c[1].y) qm |= 4u;
        if (sd_c[3].y == sd_c[2].y) qm |= 8u;
        const unsigned o1 = (unsigned)__shfl_xor((int)qm, 16);
        const unsigned o2 = (unsigned)__shfl_xor((int)qm, 32);
        const unsigned o3 = (unsigned)__shfl_xor((int)o1, 32);
        const unsigned eqmask = (qm << (q * 4)) | (o1 << ((q ^ 1) * 4)) |
                                (o2 << ((q ^ 2) * 4)) | (o3 << ((q ^ 3) * 4));
        // layer 1: gathered P~[src] + Q~[dst](+b1)
        f32x4 acc1[8];
#pragma unroll
        for (int r = 0; r < 4; ++r) {
            const bf16x8 vpr = vp[r], vqr = vq[r];
#pragma unroll
            for (int t = 0; t < 8; ++t)
                acc1[t][r] = bf2f(vpr[t]) + bf2f(vqr[t]);
        }
        // + ea @ W1c
#pragma unroll
        for (int t = 0; t < 8; ++t) {
            const bf16x8 bw = *(const bf16x8*)(sW1c + (t * 64 + lane) * 8);
            acc1[t] = __builtin_amdgcn_mfma_f32_16x16x32_bf16(aea_c, bw, acc1[t], 0, 0, 0);
        }
        // relu -> bf16 -> X~ overlay in cur buffer (vp/vq already consumed to regs)
        short* myX = bufc;
#pragma unroll
        for (int r = 0; r < 4; ++r) {
            bf16x8 vx;
#pragma unroll
            for (int t = 0; t < 8; ++t) {
                const float x = acc1[t][r];
                vx[t] = f2bf(x > 0.f ? x : 0.f);
            }
            *(bf16x8*)(myX + (q * 4 + r) * 136 + col * 8) = vx;
        }
        // layer 2
        f32x4 acc2[8];
#pragma unroll
        for (int t = 0; t < 8; ++t) {
            const float b = b2v[t];
            acc2[t] = {b, b, b, b};
        }
#pragma unroll
        for (int s = 0; s < 4; ++s) {
            const bf16x8 ax = *(const bf16x8*)(myX + col * 136 + s * 32 + q * 8);
#pragma unroll
            for (int t = 0; t < 8; ++t) {
                const bf16x8 bw = *(const bf16x8*)(sW2 + ((s * 8 + t) * 64 + lane) * 8);
                acc2[t] = __builtin_amdgcn_mfma_f32_16x16x32_bf16(ax, bw, acc2[t], 0, 0, 0);
            }
        }
        // segmented reduce + atomics
        if (eqmask == 0xFFFEu) {
#pragma unroll
            for (int t = 0; t < 8; ++t) {
                float m0 = acc2[t][0]; m0 = m0 > 0.f ? m0 : 0.f;
                float m1 = acc2[t][1]; m1 = m1 > 0.f ? m1 : 0.f;
                float m2 = acc2[t][2]; m2 = m2 > 0.f ? m2 : 0.f;
                float m3 = acc2[t][3]; m3 = m3 > 0.f ? m3 : 0.f;
                float s = (m0 + m1) + (m2 + m3);
                s += __shfl_xor(s, 16);
                s += __shfl_xor(s, 32);
                if (q == 0 && s != 0.f)
                    unsafeAtomicAdd(&agg[(size_t)sd_c[0].y * 128 + t * 16 + col], s);
            }
        } else {
            int head[4], qe[4];
#pragma unroll
            for (int r = 0; r < 4; ++r) {
                const int e = q * 4 + r;
                head[r] = !((eqmask >> e) & 1u);
                const unsigned after = ~(eqmask >> (e + 1));
                const int run = __builtin_ctz(after);
                qe[r] = (e + run) >> 2;
            }
#pragma unroll
            for (int t = 0; t < 8; ++t) {
                float m0 = acc2[t][0]; m0 = m0 > 0.f ? m0 : 0.f;
                float m1 = acc2[t][1]; m1 = m1 > 0.f ? m1 : 0.f;
                float m2 = acc2[t][2]; m2 = m2 > 0.f ? m2 : 0.f;
                float m3 = acc2[t][3]; m3 = m3 > 0.f ? m3 : 0.f;
                const float s3 = m3;
                const float s2 = m2 + ((qm & 8u) ? s3 : 0.f);
                const float s1 = m1 + ((qm & 4u) ? s2 : 0.f);
                const float s0 = m0 + ((qm & 2u) ? s1 : 0.f);
                const float p1 = __shfl_xor(s0, 16);
                const float p2 = __shfl_xor(s0, 32);
                const float p3 = __shfl_xor(p1, 32);
                const float seg[4] = {s0, s1, s2, s3};
#pragma unroll
                for (int r = 0; r < 4; ++r) {
                    if (head[r]) {
                        float tot = seg[r];
#pragma unroll
                        for (int j = 1; j < 4; ++j) {
                            if (j > q && j <= qe[r]) {
                                const int jx = j ^ q;
                                tot += (jx == 1) ? p1 : (jx == 2) ? p2 : p3;
                            }
                        }
                        if (tot != 0.f)
                            unsafeAtomicAdd(&agg[(size_t)sd_c[r].y * 128 + t * 16 + col], tot);
                    }
                }
            }
        }
        // rotate pipeline state
#pragma unroll
        for (int r = 0; r < 4; ++r) { sd_c[r] = sd_n[r]; sd_n[r] = sd_n2[r]; }
        aea_c = aea_n;
        short* tmp = bufc; bufc = bufa; bufa = tmp;
    }
}

// ---------------- update MLP + residual ----------------

__global__ __launch_bounds__(512) void update_kernel(
    const float* __restrict__ h, const float* __restrict__ agg,
    const short* __restrict__ gW, const float* __restrict__ bu1,
    const float* __restrict__ bu2, float* __restrict__ out)
{
    __shared__ short sWa[16384];
    __shared__ short sWb[16384];
    __shared__ short sW2[16384];
    __shared__ short sX[8][16 * 136];
    const int tid = threadIdx.x;
    const int wave = tid >> 6, lane = tid & 63;
    const int q = lane >> 4, col = lane & 15;
    float b1v[8], b2v[8];
#pragma unroll
    for (int t = 0; t < 8; ++t) { b1v[t] = bu1[t * 16 + col]; b2v[t] = bu2[t * 16 + col]; }
    stage_copy<2048, 512>(gW + GW_U1A, sWa, tid);
    stage_copy<2048, 512>(gW + GW_U1B, sWb, tid);
    stage_copy<2048, 512>(gW + GW_U2S, sW2, tid);
    __syncthreads();
    short* myX = &sX[wave][0];
    for (int tile = blockIdx.x * 8 + wave; tile < NN / 16; tile += gridDim.x * 8) {
        const int r0 = tile * 16;
        f32x4 acc1[8];
#pragma unroll
        for (int t = 0; t < 8; ++t) {
            const float b = b1v[t];
            acc1[t] = {b, b, b, b};
        }
#pragma unroll
        for (int s = 0; s < 4; ++s) {
            const bf16x8 ahh = cvt8(&h[(r0 + col) * 128 + s * 32 + q * 8]);
            const bf16x8 aag = cvt8(&agg[(r0 + col) * 128 + s * 32 + q * 8]);
#pragma unroll
            for (int t = 0; t < 8; ++t) {
                const bf16x8 ba = *(const bf16x8*)(sWa + ((s * 8 + t) * 64 + lane) * 8);
                const bf16x8 bb = *(const bf16x8*)(sWb + ((s * 8 + t) * 64 + lane) * 8);
                acc1[t] = __builtin_amdgcn_mfma_f32_16x16x32_bf16(ahh, ba, acc1[t], 0, 0, 0);
                acc1[t] = __builtin_amdgcn_mfma_f32_16x16x32_bf16(aag, bb, acc1[t], 0, 0, 0);
            }
        }
#pragma unroll
        for (int r = 0; r < 4; ++r) {
            bf16x8 vx;
#pragma unroll
            for (int t = 0; t < 8; ++t) {
                const float x = acc1[t][r];
                vx[t] = f2bf(x > 0.f ? x : 0.f);
            }
            *(bf16x8*)(myX + (q * 4 + r) * 136 + col * 8) = vx;
        }
        f32x4 acc2[8];
#pragma unroll
        for (int t = 0; t < 8; ++t) {
            const float b = b2v[t];
#pragma unroll
            for (int r = 0; r < 4; ++r)
                acc2[t][r] = b + h[(r0 + q * 4 + r) * 128 + t * 16 + col];
        }
#pragma unroll
        for (int s = 0; s < 4; ++s) {
            const bf16x8 ax = *(const bf16x8*)(myX + col * 136 + s * 32 + q * 8);
#pragma unroll
            for (int t = 0; t < 8; ++t) {
                const bf16x8 bw = *(const bf16x8*)(sW2 + ((s * 8 + t) * 64 + lane) * 8);
                acc2[t] = __builtin_amdgcn_mfma_f32_16x16x32_bf16(ax, bw, acc2[t], 0, 0, 0);
            }
        }
#pragma unroll
        for (int t = 0; t < 8; ++t)
#pragma unroll
            for (int r = 0; r < 4; ++r)
                out[(r0 + q * 4 + r) * 128 + t * 16 + col] = acc2[t][r];
    }
}

extern "C" void kernel_launch(void* const* d_in, const int* in_sizes, int n_in,
                              void* d_out, int out_size, void* d_ws, size_t ws_size,
                              hipStream_t stream) {
    const float* h   = (const float*)d_in[0];
    const float* ea  = (const float*)d_in[1];
    const float* Wm1 = (const float*)d_in[2];
    const float* bm1 = (const float*)d_in[3];
    const float* Wm2 = (const float*)d_in[4];
    const float* bm2 = (const float*)d_in[5];
    const float* Wu1 = (const float*)d_in[6];
    const float* bu1 = (const float*)d_in[7];
    const float* Wu2 = (const float*)d_in[8];
    const float* bu2 = (const float*)d_in[9];
    const int* eidx  = (const int*)d_in[10];
    float* out = (float*)d_out;

    short* gW  = (short*)d_ws;                       // 102400 shorts
    short* Pb  = gW + GW_TOT;                        // NN*128 bf16
    short* Qb  = Pb + (size_t)NN * 128;              // NN*128 bf16
    float* agg = (float*)(Qb + (size_t)NN * 128);    // NN*128 fp32
    int* cnt    = (int*)(agg + (size_t)NN * 128);    // NN
    int* part   = cnt + NN;                          // NN
    int* bsum   = part + NN;                         // 64
    int* cursor = bsum + 64;                         // NN
    int2* sd2   = (int2*)(cursor + NN);              // NE int2
    short* eb   = (short*)(sd2 + NE);                // NE*32 bf16 (sorted edge attrs)

    const int NB_SCAN = (NN + 1023) / 1024;  // 49
    const int NB_E = (NE + 255) / 256;       // 3125

    hipMemsetAsync(cnt, 0, (size_t)NN * sizeof(int), stream);
    hipMemsetAsync(agg, 0, (size_t)NN * 128 * sizeof(float), stream);
    mega_kernel<<<512 + 50 + NB_E, 256, 0, stream>>>(h, Wm1, bm1, Wm2, Wu1, Wu2,
                                                     eidx, gW, Pb, Qb, cnt);
    scan1_kernel<<<NB_SCAN, 1024, 0, stream>>>(cnt, part, bsum);
    scan23_kernel<<<NB_SCAN, 1024, 0, stream>>>(part, bsum, cursor);
    scatter_kernel<<<NB_E, 256, 0, stream>>>(eidx, cursor, ea, sd2, eb);
    edge_kernel<<<256, 448, 0, stream>>>(Pb, Qb, eb, gW, bm2, sd2, agg);
    update_kernel<<<256, 512, 0, stream>>>(h, agg, gW, bu1, bu2, out);
}

// Round 4
// 461.676 us; speedup vs baseline: 1.3795x; 1.2353x over previous
//
#include <hip/hip_runtime.h>

#define NN 50000
#define NE 800000

typedef __attribute__((ext_vector_type(8))) short bf16x8;
typedef __attribute__((ext_vector_type(4))) float f32x4;

__device__ __forceinline__ short f2bf(float f) {
    union { float f; unsigned u; } v; v.f = f;
    return (short)((v.u + 0x7fffu + ((v.u >> 16) & 1u)) >> 16);
}

__device__ __forceinline__ float bf2f(short s) {
    union { unsigned u; float f; } v;
    v.u = ((unsigned)(unsigned short)s) << 16;
    return v.f;
}

// HW packed f32->bf16 (RNE), 1 instr per 2 values (vs ~4 VALU each in sw f2bf).
__device__ __forceinline__ unsigned cvtpk(float lo, float hi) {
    unsigned r;
    asm("v_cvt_pk_bf16_f32 %0, %1, %2" : "=v"(r) : "v"(lo), "v"(hi));
    return r;
}

union bf8u { unsigned u[4]; bf16x8 v; };

__device__ __forceinline__ bf16x8 cvt8(const float* __restrict__ p) {
    const f32x4 a = *(const f32x4*)p;
    const f32x4 b = *(const f32x4*)(p + 4);
    bf8u r;
    r.u[0] = cvtpk(a[0], a[1]); r.u[1] = cvtpk(a[2], a[3]);
    r.u[2] = cvtpk(b[0], b[1]); r.u[3] = cvtpk(b[2], b[3]);
    return r.v;
}

// Async global->LDS DMA, 16B per lane: per-lane global addr, wave-uniform LDS base;
// HW writes lane i's data at base + i*16. Tracked by vmcnt. Cannot be sunk/remat'd.
__device__ __forceinline__ void gld_lds16(const short* g, short* l) {
    __builtin_amdgcn_global_load_lds(
        (const __attribute__((address_space(1))) void*)g,
        (__attribute__((address_space(3))) void*)l, 16, 0, 0);
}

// gW slot map (slot = 8 shorts at gW + slot*8):
// [0,2048) Wm1a | [2048,4096) Wm1b | [4096,4608) W1c | [4608,6656) Wm2 sigma
// [6656,8704) Wu1a | [8704,10752) Wu1b | [10752,12800) Wu2 sigma
#define GW_M1A 0
#define GW_M1B 16384
#define GW_1C  32768
#define GW_M2S 36864
#define GW_U1A 53248
#define GW_U1B 69632
#define GW_U2S 86016
#define GW_TOT 102400

// Stage W (KROWS x 128 row-major fp32) -> LDS bf16 MFMA B-fragments (node_pq path).
template<int KROWS, int NTHREADS>
__device__ __forceinline__ void stage_w(const float* __restrict__ W, short* lds, int tid) {
    constexpr int NSLOT = (KROWS / 32) * 8 * 64;
#pragma unroll 1
    for (int slot = tid; slot < NSLOT; slot += NTHREADS) {
        const int f = slot >> 6, l = slot & 63;
        const int s = f >> 3, t = f & 7;
        const int k0 = 32 * s + ((l >> 4) << 3);
        const int n = 16 * t + (l & 15);
        float w[8];
#pragma unroll
        for (int j = 0; j < 8; ++j) w[j] = W[(k0 + j) * 128 + n];
        bf8u v;
#pragma unroll
        for (int j = 0; j < 4; ++j) v.u[j] = cvtpk(w[2 * j], w[2 * j + 1]);
        *(bf16x8*)(lds + slot * 8) = v.v;
    }
}

template<int NSLOT, int NTHREADS>
__device__ __forceinline__ void stage_copy(const short* __restrict__ g, short* lds, int tid) {
#pragma unroll 1
    for (int s = tid; s < NSLOT; s += NTHREADS) {
        *(bf16x8*)(lds + (size_t)s * 8) = *(const bf16x8*)(g + (size_t)s * 8);
    }
}

// ---------------- mega kernel: node_pq (blocks 0..511) | preswz (512..561) | hist (562..) ----------------

__global__ __launch_bounds__(256) void mega_kernel(
    const float* __restrict__ h, const float* __restrict__ Wm1,
    const float* __restrict__ bm1, const float* __restrict__ Wm2,
    const float* __restrict__ Wu1, const float* __restrict__ Wu2,
    const int* __restrict__ eidx, short* __restrict__ gW,
    short* __restrict__ Pb, short* __restrict__ Qb, int* __restrict__ cnt)
{
    const int b = blockIdx.x;
    const int tid = threadIdx.x;
    if (b < 512) {
        // ---- node_pq: P~ = h@Wm1a (sigma bf16), Q~ = h@Wm1b + bm1 ----
        __shared__ short sWa[16384];
        __shared__ short sWb[16384];
        stage_w<128, 256>(Wm1, sWa, tid);
        stage_w<128, 256>(Wm1 + 128 * 128, sWb, tid);
        __syncthreads();
        const int wave = tid >> 6, lane = tid & 63;
        const int q = lane >> 4, col = lane & 15;
        float b1v[8];
#pragma unroll
        for (int t = 0; t < 8; ++t) b1v[t] = bm1[t * 16 + col];
        for (int tile = b * 4 + wave; tile < NN / 16; tile += 2048) {
            const int r0 = tile * 16;
            f32x4 aP[8], aQ[8];
#pragma unroll
            for (int t = 0; t < 8; ++t) {
                aP[t] = {0.f, 0.f, 0.f, 0.f};
                const float bb = b1v[t];
                aQ[t] = {bb, bb, bb, bb};
            }
#pragma unroll
            for (int s = 0; s < 4; ++s) {
                const bf16x8 ah = cvt8(&h[(r0 + col) * 128 + s * 32 + q * 8]);
#pragma unroll
                for (int t = 0; t < 8; ++t) {
                    const bf16x8 ba = *(const bf16x8*)(sWa + ((s * 8 + t) * 64 + lane) * 8);
                    const bf16x8 bb = *(const bf16x8*)(sWb + ((s * 8 + t) * 64 + lane) * 8);
                    aP[t] = __builtin_amdgcn_mfma_f32_16x16x32_bf16(ah, ba, aP[t], 0, 0, 0);
                    aQ[t] = __builtin_amdgcn_mfma_f32_16x16x32_bf16(ah, bb, aQ[t], 0, 0, 0);
                }
            }
#pragma unroll
            for (int r = 0; r < 4; ++r) {
                const size_t row = (size_t)(r0 + q * 4 + r) * 128;
                bf8u vp, vq;
#pragma unroll
                for (int j = 0; j < 4; ++j) {
                    vp.u[j] = cvtpk(aP[2 * j][r], aP[2 * j + 1][r]);
                    vq.u[j] = cvtpk(aQ[2 * j][r], aQ[2 * j + 1][r]);
                }
                *(bf16x8*)(Pb + row + col * 8) = vp.v;
                *(bf16x8*)(Qb + row + col * 8) = vq.v;
            }
        }
    } else if (b < 562) {
        // ---- preswz: weights -> global bf16 fragments ----
        const int slot = (b - 512) * 256 + tid;
        if (slot < 12800) {
            const float* W; int local; bool sigma = false;
            if (slot < 2048)       { W = Wm1;             local = slot; }
            else if (slot < 4096)  { W = Wm1 + 128 * 128; local = slot - 2048; }
            else if (slot < 4608)  { W = Wm1 + 256 * 128; local = slot - 4096; }
            else if (slot < 6656)  { W = Wm2;             local = slot - 4608; sigma = true; }
            else if (slot < 8704)  { W = Wu1;             local = slot - 6656; }
            else if (slot < 10752) { W = Wu1 + 128 * 128; local = slot - 8704; }
            else                   { W = Wu2;             local = slot - 10752; sigma = true; }
            const int f = local >> 6, l = local & 63;
            const int s = f >> 3, t = f & 7;
            const int k0 = 32 * s + ((l >> 4) << 3);
            const int n = 16 * t + (l & 15);
            float w[8];
#pragma unroll
            for (int j = 0; j < 8; ++j) {
                int k = k0 + j;
                if (sigma) k = (k & 7) * 16 + (k >> 3);
                w[j] = W[k * 128 + n];
            }
            bf8u v;
#pragma unroll
            for (int j = 0; j < 4; ++j) v.u[j] = cvtpk(w[2 * j], w[2 * j + 1]);
            *(bf16x8*)(gW + (size_t)slot * 8) = v.v;
        }
    } else {
        // ---- hist ----
        const int e = (b - 562) * 256 + tid;
        if (e < NE) atomicAdd(&cnt[eidx[NE + e]], 1);
    }
}

// ---------------- scan ----------------

__global__ __launch_bounds__(1024) void scan1_kernel(const int* __restrict__ cnt,
                                                     int* __restrict__ part,
                                                     int* __restrict__ bsum) {
    __shared__ int s[1024];
    const int t = threadIdx.x;
    const int i = blockIdx.x * 1024 + t;
    const int v = (i < NN) ? cnt[i] : 0;
    int x = v;
    s[t] = x;
    __syncthreads();
    for (int off = 1; off < 1024; off <<= 1) {
        const int y = (t >= off) ? s[t - off] : 0;
        __syncthreads();
        x += y;
        s[t] = x;
        __syncthreads();
    }
    if (i < NN) part[i] = x - v;
    if (t == 1023) bsum[blockIdx.x] = x;
}

__global__ __launch_bounds__(1024) void scan23_kernel(const int* __restrict__ part,
                                                      const int* __restrict__ bsum,
                                                      int* __restrict__ cursor) {
    __shared__ int off;
    if (threadIdx.x == 0) {
        int a = 0;
        for (int bb = 0; bb < (int)blockIdx.x; ++bb) a += bsum[bb];
        off = a;
    }
    __syncthreads();
    const int i = blockIdx.x * 1024 + threadIdx.x;
    if (i < NN) cursor[i] = part[i] + off;
}

// ---------------- scatter: perm edges to sorted order; also permute+cvt ea -> eb (bf16) ----------------

__global__ void scatter_kernel(const int* __restrict__ eidx, int* __restrict__ cursor,
                               const float* __restrict__ ea,
                               int2* __restrict__ sd2, short* __restrict__ eb) {
    const int e = blockIdx.x * blockDim.x + threadIdx.x;
    if (e < NE) {
        const int d = eidx[NE + e];
        const int pos = atomicAdd(&cursor[d], 1);
        sd2[pos] = make_int2(eidx[e], d);
        const float* src = ea + (size_t)e * 32;
        short* dst = eb + (size_t)pos * 32;
#pragma unroll
        for (int j = 0; j < 4; ++j) {
            const f32x4 a = *(const f32x4*)(src + j * 8);
            const f32x4 bq = *(const f32x4*)(src + j * 8 + 4);
            bf8u v;
            v.u[0] = cvtpk(a[0], a[1]);  v.u[1] = cvtpk(a[2], a[3]);
            v.u[2] = cvtpk(bq[0], bq[1]); v.u[3] = cvtpk(bq[2], bq[3]);
            *(bf16x8*)(dst + j * 8) = v.v;
        }
    }
}

// ---------------- edge kernel: chunked tiles + LDS-DMA pipeline, atomic-decoupled wait ----
// Round-3 post-mortem: the per-iter s_waitcnt vmcnt(0) sat AFTER the atomic burst of the
// previous tile (vmcnt retires in order), so every tile paid the atomic L2-retire latency.
// Fix: consume-side ds_read of the NEXT tile's staged buffer moved to BEFORE this tile's
// atomics. Order per iter: DMA(t+1) early -> compute(t) -> vmcnt(0) [waits DMA issued
// ~2.5k cyc ago + atomics(t-1) issued a full iteration ago - both drained] -> ds_read ->
// atomics(t). LDS alias analysis pins the ds_reads (can't sink past next iter's DMA into
// the same pool); asm memory clobber keeps atomics after the wait. vp/vq live across the
// atomics: +32 VGPR, fine at 7 waves/CU (launch_bounds min-waves 1 to unpin allocator).
#define WPB 7
#define TPW 28  // ceil(50000 / (256*7))

__global__ __launch_bounds__(448, 1) void edge_kernel(
    const short* __restrict__ Pb, const short* __restrict__ Qb,
    const short* __restrict__ eb, const short* __restrict__ gW,
    const float* __restrict__ bm2,
    const int2* __restrict__ sd2, float* __restrict__ agg)
{
    __shared__ short sW2[16384];
    __shared__ short sW1c[4096];
    __shared__ short sPool[WPB][2][4096];
    const int tid = threadIdx.x;
    const int wave = tid >> 6, lane = tid & 63;
    const int q = lane >> 4, col = lane & 15;
    const int NT = NE / 16;
    float b2v[8];
#pragma unroll
    for (int t = 0; t < 8; ++t) b2v[t] = bm2[t * 16 + col];
    stage_copy<2048, 448>(gW + GW_M2S, sW2, tid);
    stage_copy<512, 448>(gW + GW_1C, sW1c, tid);

    const int wg = blockIdx.x * WPB + wave;
    const int t_begin = wg * TPW;
    const int t_end = (t_begin + TPW < NT) ? (t_begin + TPW) : NT;
    const bool act = t_begin < t_end;

    short* bufc = &sPool[wave][0][0];
    short* bufa = &sPool[wave][1][0];
    int2 sd_c[4], sd_n[4];
    bf16x8 aea_c;
    bf16x8 vp[4], vq[4];

    if (act) {
        // prologue: sd[t0]; DMA(t0)->bufc; sd[t0+1]; aea[t0]
        {
            const int e0 = t_begin * 16;
            const int4 a0 = *(const int4*)(sd2 + e0 + q * 4);
            const int4 a1 = *(const int4*)(sd2 + e0 + q * 4 + 2);
            sd_c[0] = make_int2(a0.x, a0.y); sd_c[1] = make_int2(a0.z, a0.w);
            sd_c[2] = make_int2(a1.x, a1.y); sd_c[3] = make_int2(a1.z, a1.w);
        }
#pragma unroll
        for (int r = 0; r < 4; ++r) {
            gld_lds16(Pb + (size_t)sd_c[r].x * 128 + col * 8, bufc + r * 512);
            gld_lds16(Qb + (size_t)sd_c[r].y * 128 + col * 8, bufc + 2048 + r * 512);
        }
        {
            const int t1 = (t_begin + 1 < t_end) ? t_begin + 1 : t_begin;
            const int e1 = t1 * 16;
            const int4 a0 = *(const int4*)(sd2 + e1 + q * 4);
            const int4 a1 = *(const int4*)(sd2 + e1 + q * 4 + 2);
            sd_n[0] = make_int2(a0.x, a0.y); sd_n[1] = make_int2(a0.z, a0.w);
            sd_n[2] = make_int2(a1.x, a1.y); sd_n[3] = make_int2(a1.z, a1.w);
        }
        aea_c = *(const bf16x8*)(eb + (size_t)(t_begin * 16 + col) * 32 + q * 8);
    }
    __syncthreads();
    if (act) {
        asm volatile("s_waitcnt vmcnt(0)" ::: "memory");
#pragma unroll
        for (int r = 0; r < 4; ++r) {
            vp[r] = *(const bf16x8*)(bufc + r * 512 + lane * 8);
            vq[r] = *(const bf16x8*)(bufc + 2048 + r * 512 + lane * 8);
        }
    }

    for (int tile = t_begin; tile < t_end; ++tile) {
        const int tn = (tile + 1 < t_end) ? tile + 1 : tile;
        // 1. issue next-tile staging into alt buffer (latency spans whole iteration)
#pragma unroll
        for (int r = 0; r < 4; ++r) {
            gld_lds16(Pb + (size_t)sd_n[r].x * 128 + col * 8, bufa + r * 512);
            gld_lds16(Qb + (size_t)sd_n[r].y * 128 + col * 8, bufa + 2048 + r * 512);
        }
        // 2. register-prefetch next aea (streamed, chunked) and sd[tile+2]
        const bf16x8 aea_n = *(const bf16x8*)(eb + (size_t)(tn * 16 + col) * 32 + q * 8);
        int2 sd_n2[4];
        {
            const int t2 = (tile + 2 < t_end) ? tile + 2 : t_end - 1;
            const int e2 = t2 * 16;
            const int4 a0 = *(const int4*)(sd2 + e2 + q * 4);
            const int4 a1 = *(const int4*)(sd2 + e2 + q * 4 + 2);
            sd_n2[0] = make_int2(a0.x, a0.y); sd_n2[1] = make_int2(a0.z, a0.w);
            sd_n2[2] = make_int2(a1.x, a1.y); sd_n2[3] = make_int2(a1.z, a1.w);
        }
        // 3. run-structure mask for current tile
        const int prev3 = __shfl_up(sd_c[3].y, 16);
        unsigned qm = 0;
        if (q > 0 && sd_c[0].y == prev3) qm |= 1u;
        if (sd_c[1].y == sd_c[0].y) qm |= 2u;
        if (sd_c[2].y == sd_c[1].y) qm |= 4u;
        if (sd_c[3].y == sd_c[2].y) qm |= 8u;
        const unsigned o1 = (unsigned)__shfl_xor((int)qm, 16);
        const unsigned o2 = (unsigned)__shfl_xor((int)qm, 32);
        const unsigned o3 = (unsigned)__shfl_xor((int)o1, 32);
        const unsigned eqmask = (qm << (q * 4)) | (o1 << ((q ^ 1) * 4)) |
                                (o2 << ((q ^ 2) * 4)) | (o3 << ((q ^ 3) * 4));
        // 4. layer 1: gathered P~[src] + Q~[dst](+b1)
        f32x4 acc1[8];
#pragma unroll
        for (int r = 0; r < 4; ++r) {
            const bf16x8 vpr = vp[r], vqr = vq[r];
#pragma unroll
            for (int t = 0; t < 8; ++t)
                acc1[t][r] = bf2f(vpr[t]) + bf2f(vqr[t]);
        }
#pragma unroll
        for (int t = 0; t < 8; ++t) {
            const bf16x8 bw = *(const bf16x8*)(sW1c + (t * 64 + lane) * 8);
            acc1[t] = __builtin_amdgcn_mfma_f32_16x16x32_bf16(aea_c, bw, acc1[t], 0, 0, 0);
        }
        // 5. relu -> bf16 (cvt_pk) -> X~ overlay in cur buffer
        short* myX = bufc;
#pragma unroll
        for (int r = 0; r < 4; ++r) {
            float m[8];
#pragma unroll
            for (int t = 0; t < 8; ++t) { const float x = acc1[t][r]; m[t] = x > 0.f ? x : 0.f; }
            bf8u vx;
#pragma unroll
            for (int j = 0; j < 4; ++j) vx.u[j] = cvtpk(m[2 * j], m[2 * j + 1]);
            *(bf16x8*)(myX + (q * 4 + r) * 136 + col * 8) = vx.v;
        }
        // 6. layer 2
        f32x4 acc2[8];
#pragma unroll
        for (int t = 0; t < 8; ++t) {
            const float b = b2v[t];
            acc2[t] = {b, b, b, b};
        }
#pragma unroll
        for (int s = 0; s < 4; ++s) {
            const bf16x8 ax = *(const bf16x8*)(myX + col * 136 + s * 32 + q * 8);
#pragma unroll
            for (int t = 0; t < 8; ++t) {
                const bf16x8 bw = *(const bf16x8*)(sW2 + ((s * 8 + t) * 64 + lane) * 8);
                acc2[t] = __builtin_amdgcn_mfma_f32_16x16x32_bf16(ax, bw, acc2[t], 0, 0, 0);
            }
        }
        // 7. wait for DMA(t+1) (issued at step 1, ~one compute phase ago) + late-read
        //    next tile's P/Q into regs BEFORE this tile's atomics are issued.
        asm volatile("s_waitcnt vmcnt(0)" ::: "memory");
#pragma unroll
        for (int r = 0; r < 4; ++r) {
            vp[r] = *(const bf16x8*)(bufa + r * 512 + lane * 8);
            vq[r] = *(const bf16x8*)(bufa + 2048 + r * 512 + lane * 8);
        }
        // 8. segmented reduce + atomics (retire during next iteration's compute)
        if (eqmask == 0xFFFEu) {
#pragma unroll
            for (int t = 0; t < 8; ++t) {
                float m0 = acc2[t][0]; m0 = m0 > 0.f ? m0 : 0.f;
                float m1 = acc2[t][1]; m1 = m1 > 0.f ? m1 : 0.f;
                float m2 = acc2[t][2]; m2 = m2 > 0.f ? m2 : 0.f;
                float m3 = acc2[t][3]; m3 = m3 > 0.f ? m3 : 0.f;
                float s = (m0 + m1) + (m2 + m3);
                s += __shfl_xor(s, 16);
                s += __shfl_xor(s, 32);
                if (q == 0 && s != 0.f)
                    unsafeAtomicAdd(&agg[(size_t)sd_c[0].y * 128 + t * 16 + col], s);
            }
        } else {
            int head[4], qe[4];
#pragma unroll
            for (int r = 0; r < 4; ++r) {
                const int e = q * 4 + r;
                head[r] = !((eqmask >> e) & 1u);
                const unsigned after = ~(eqmask >> (e + 1));
                const int run = __builtin_ctz(after);
                qe[r] = (e + run) >> 2;
            }
#pragma unroll
            for (int t = 0; t < 8; ++t) {
                float m0 = acc2[t][0]; m0 = m0 > 0.f ? m0 : 0.f;
                float m1 = acc2[t][1]; m1 = m1 > 0.f ? m1 : 0.f;
                float m2 = acc2[t][2]; m2 = m2 > 0.f ? m2 : 0.f;
                float m3 = acc2[t][3]; m3 = m3 > 0.f ? m3 : 0.f;
                const float s3 = m3;
                const float s2 = m2 + ((qm & 8u) ? s3 : 0.f);
                const float s1 = m1 + ((qm & 4u) ? s2 : 0.f);
                const float s0 = m0 + ((qm & 2u) ? s1 : 0.f);
                const float p1 = __shfl_xor(s0, 16);
                const float p2 = __shfl_xor(s0, 32);
                const float p3 = __shfl_xor(p1, 32);
                const float seg[4] = {s0, s1, s2, s3};
#pragma unroll
                for (int r = 0; r < 4; ++r) {
                    if (head[r]) {
                        float tot = seg[r];
#pragma unroll
                        for (int j = 1; j < 4; ++j) {
                            if (j > q && j <= qe[r]) {
                                const int jx = j ^ q;
                                tot += (jx == 1) ? p1 : (jx == 2) ? p2 : p3;
                            }
                        }
                        if (tot != 0.f)
                            unsafeAtomicAdd(&agg[(size_t)sd_c[r].y * 128 + t * 16 + col], tot);
                    }
                }
            }
        }
        // 9. rotate pipeline state
#pragma unroll
        for (int r = 0; r < 4; ++r) { sd_c[r] = sd_n[r]; sd_n[r] = sd_n2[r]; }
        aea_c = aea_n;
        short* tmp = bufc; bufc = bufa; bufa = tmp;
    }
}

// ---------------- update MLP + residual ----------------
// Wu1b/Wu2 fragments read directly from gW (200KB, L2-resident, coalesced 1KB/instr):
// LDS drops 133K->67.6K -> 2 blocks/CU (16 waves) for latency hiding. Grid 512.

__global__ __launch_bounds__(512) void update_kernel(
    const float* __restrict__ h, const float* __restrict__ agg,
    const short* __restrict__ gW, const float* __restrict__ bu1,
    const float* __restrict__ bu2, float* __restrict__ out)
{
    __shared__ short sWa[16384];
    __shared__ short sX[8][16 * 136];
    const int tid = threadIdx.x;
    const int wave = tid >> 6, lane = tid & 63;
    const int q = lane >> 4, col = lane & 15;
    float b1v[8], b2v[8];
#pragma unroll
    for (int t = 0; t < 8; ++t) { b1v[t] = bu1[t * 16 + col]; b2v[t] = bu2[t * 16 + col]; }
    stage_copy<2048, 512>(gW + GW_U1A, sWa, tid);
    __syncthreads();
    const short* gWb = gW + GW_U1B;
    const short* gW2 = gW + GW_U2S;
    short* myX = &sX[wave][0];
    for (int tile = blockIdx.x * 8 + wave; tile < NN / 16; tile += gridDim.x * 8) {
        const int r0 = tile * 16;
        f32x4 acc1[8];
#pragma unroll
        for (int t = 0; t < 8; ++t) {
            const float b = b1v[t];
            acc1[t] = {b, b, b, b};
        }
#pragma unroll
        for (int s = 0; s < 4; ++s) {
            const bf16x8 ahh = cvt8(&h[(r0 + col) * 128 + s * 32 + q * 8]);
            const bf16x8 aag = cvt8(&agg[(r0 + col) * 128 + s * 32 + q * 8]);
#pragma unroll
            for (int t = 0; t < 8; ++t) {
                const bf16x8 ba = *(const bf16x8*)(sWa + ((s * 8 + t) * 64 + lane) * 8);
                const bf16x8 bb = *(const bf16x8*)(gWb + ((s * 8 + t) * 64 + lane) * 8);
                acc1[t] = __builtin_amdgcn_mfma_f32_16x16x32_bf16(ahh, ba, acc1[t], 0, 0, 0);
                acc1[t] = __builtin_amdgcn_mfma_f32_16x16x32_bf16(aag, bb, acc1[t], 0, 0, 0);
            }
        }
#pragma unroll
        for (int r = 0; r < 4; ++r) {
            float m[8];
#pragma unroll
            for (int t = 0; t < 8; ++t) { const float x = acc1[t][r]; m[t] = x > 0.f ? x : 0.f; }
            bf8u vx;
#pragma unroll
            for (int j = 0; j < 4; ++j) vx.u[j] = cvtpk(m[2 * j], m[2 * j + 1]);
            *(bf16x8*)(myX + (q * 4 + r) * 136 + col * 8) = vx.v;
        }
        f32x4 acc2[8];
#pragma unroll
        for (int t = 0; t < 8; ++t) {
            const float b = b2v[t];
#pragma unroll
            for (int r = 0; r < 4; ++r)
                acc2[t][r] = b + h[(r0 + q * 4 + r) * 128 + t * 16 + col];
        }
#pragma unroll
        for (int s = 0; s < 4; ++s) {
            const bf16x8 ax = *(const bf16x8*)(myX + col * 136 + s * 32 + q * 8);
#pragma unroll
            for (int t = 0; t < 8; ++t) {
                const bf16x8 bw = *(const bf16x8*)(gW2 + ((s * 8 + t) * 64 + lane) * 8);
                acc2[t] = __builtin_amdgcn_mfma_f32_16x16x32_bf16(ax, bw, acc2[t], 0, 0, 0);
            }
        }
#pragma unroll
        for (int t = 0; t < 8; ++t)
#pragma unroll
            for (int r = 0; r < 4; ++r)
                out[(r0 + q * 4 + r) * 128 + t * 16 + col] = acc2[t][r];
    }
}

extern "C" void kernel_launch(void* const* d_in, const int* in_sizes, int n_in,
                              void* d_out, int out_size, void* d_ws, size_t ws_size,
                              hipStream_t stream) {
    const float* h   = (const float*)d_in[0];
    const float* ea  = (const float*)d_in[1];
    const float* Wm1 = (const float*)d_in[2];
    const float* bm1 = (const float*)d_in[3];
    const float* Wm2 = (const float*)d_in[4];
    const float* bm2 = (const float*)d_in[5];
    const float* Wu1 = (const float*)d_in[6];
    const float* bu1 = (const float*)d_in[7];
    const float* Wu2 = (const float*)d_in[8];
    const float* bu2 = (const float*)d_in[9];
    const int* eidx  = (const int*)d_in[10];
    float* out = (float*)d_out;

    short* gW  = (short*)d_ws;                       // 102400 shorts
    short* Pb  = gW + GW_TOT;                        // NN*128 bf16
    short* Qb  = Pb + (size_t)NN * 128;              // NN*128 bf16
    float* agg = (float*)(Qb + (size_t)NN * 128);    // NN*128 fp32
    int* cnt    = (int*)(agg + (size_t)NN * 128);    // NN
    int* part   = cnt + NN;                          // NN
    int* bsum   = part + NN;                         // 64
    int* cursor = bsum + 64;                         // NN
    int2* sd2   = (int2*)(cursor + NN);              // NE int2
    short* eb   = (short*)(sd2 + NE);                // NE*32 bf16 (sorted edge attrs)

    const int NB_SCAN = (NN + 1023) / 1024;  // 49
    const int NB_E = (NE + 255) / 256;       // 3125

    hipMemsetAsync(cnt, 0, (size_t)NN * sizeof(int), stream);
    hipMemsetAsync(agg, 0, (size_t)NN * 128 * sizeof(float), stream);
    mega_kernel<<<512 + 50 + NB_E, 256, 0, stream>>>(h, Wm1, bm1, Wm2, Wu1, Wu2,
                                                     eidx, gW, Pb, Qb, cnt);
    scan1_kernel<<<NB_SCAN, 1024, 0, stream>>>(cnt, part, bsum);
    scan23_kernel<<<NB_SCAN, 1024, 0, stream>>>(part, bsum, cursor);
    scatter_kernel<<<NB_E, 256, 0, stream>>>(eidx, cursor, ea, sd2, eb);
    edge_kernel<<<256, 448, 0, stream>>>(Pb, Qb, eb, gW, bm2, sd2, agg);
    update_kernel<<<512, 512, 0, stream>>>(h, agg, gW, bu1, bu2, out);
}